// Round 10
// baseline (19437.871 us; speedup 1.0000x reference)
//
#include <hip/hip_runtime.h>
#include <hip/hip_bf16.h>
#include <math.h>

#define KW 24
#define BSZn 64
#define PLY 32
#define BROWS 1536            // BSZ*KW rows per task
#define RTOT 4608             // 3*BROWS

typedef __attribute__((ext_vector_type(8))) short short8v;  // 8 bf16 (4 VGPRs)
typedef __attribute__((ext_vector_type(4))) float f32x4;

__device__ __forceinline__ float sigmoidf_(float x) { return 1.0f / (1.0f + expf(-x)); }

// exact 3-way bf16 split: v = s0 + s1 + s2 + O(2^-26 v)
__device__ __forceinline__ void split3(float v, ushort* a, ushort* b, ushort* c)
{
    __hip_bfloat16 h1 = __float2bfloat16(v);  float f1 = __bfloat162float(h1);
    float r1 = v - f1;
    __hip_bfloat16 h2 = __float2bfloat16(r1); float f2 = __bfloat162float(h2);
    float r2 = r1 - f2;
    __hip_bfloat16 h3 = __float2bfloat16(r2);
    *a = *(ushort*)&h1; *b = *(ushort*)&h2; *c = *(ushort*)&h3;
}

// ---- weights prep (R9-proven) ----
// Gate cols: n = ublk*64 + gate*16 + ui ; source row = gate*512 + ublk*16 + ui.
__global__ void prep_split(const float* __restrict__ W_ih, const float* __restrict__ W_hh,
                           const float* __restrict__ Wq,
                           const float* __restrict__ b_ih, const float* __restrict__ b_hh,
                           ushort* __restrict__ Wg0, ushort* __restrict__ Wg1, ushort* __restrict__ Wg2,
                           ushort* __restrict__ Wq0, ushort* __restrict__ Wq1, ushort* __restrict__ Wq2,
                           float* __restrict__ biasG)
{
    int n = blockIdx.x, tid = threadIdx.x;     // 0..2559
    if (n < 2048) {
        int ublk = n >> 6, gate = (n >> 4) & 3, ui = n & 15;
        int src = gate * 512 + ublk * 16 + ui;
        for (int k = tid; k < 1024; k += 256) {
            float v = (k < 512) ? W_ih[(size_t)src * 512 + k]
                                : W_hh[(size_t)src * 512 + (k - 512)];
            ushort s0, s1, s2; split3(v, &s0, &s1, &s2);
            Wg0[(size_t)n * 1024 + k] = s0;
            Wg1[(size_t)n * 1024 + k] = s1;
            Wg2[(size_t)n * 1024 + k] = s2;
        }
        if (tid == 0) biasG[src] = b_ih[src] + b_hh[src];
    } else {
        int n2 = n - 2048;
        for (int k = tid; k < 512; k += 256) {
            ushort s0, s1, s2; split3(Wq[(size_t)n2 * 512 + k], &s0, &s1, &s2);
            Wq0[(size_t)n2 * 512 + k] = s0;
            Wq1[(size_t)n2 * 512 + k] = s1;
            Wq2[(size_t)n2 * 512 + k] = s2;
        }
    }
}

// ---- init (R9-proven): cst = h0; hs[1] = split(h0); xs = split(init_embed) ----
__global__ void initsplit(const float* __restrict__ home, const float* __restrict__ vis,
                          const float* __restrict__ team, const float* __restrict__ init_embed,
                          float* __restrict__ cst,
                          ushort* __restrict__ h0_, ushort* __restrict__ h1_, ushort* __restrict__ h2_,
                          ushort* __restrict__ x0_, ushort* __restrict__ x1_, ushort* __restrict__ x2_)
{
    int row = blockIdx.x, tid = threadIdx.x;
    int tau = row / BROWS, r = row % BROWS;
    const float* enc = (tau == 0) ? home : (tau == 1) ? vis : team;
    const float* base = enc + ((size_t)((r % KW) * BSZn + r / KW) * PLY) * 512;
    for (int e = tid; e < 512; e += 256) {
        float s = 0.0f;
        for (int p = 0; p < PLY; ++p) s += base[(size_t)p * 512 + e];
        size_t o = (size_t)row * 512 + e;
        cst[o] = s;
        ushort a, b, c;
        split3(s, &a, &b, &c);
        h0_[o] = a; h1_[o] = b; h2_[o] = c;
        split3(init_embed[e], &a, &b, &c);
        x0_[o] = a; x1_[o] = b; x2_[o] = c;
    }
}

// ---- gather x_{t+1} and split (R9-proven) ----
__global__ void xprep(const float* __restrict__ home, const float* __restrict__ vis,
                      const float* __restrict__ team,
                      const int* __restrict__ hidx, const int* __restrict__ vidx,
                      const int* __restrict__ tidx,
                      ushort* __restrict__ x0_, ushort* __restrict__ x1_, ushort* __restrict__ x2_,
                      int t)
{
    int row = blockIdx.x, tid = threadIdx.x;
    int tau = row / BROWS, r = row % BROWS;
    const float* enc = (tau == 0) ? home : (tau == 1) ? vis : team;
    const int* idx = (tau == 0) ? hidx : (tau == 1) ? vidx : tidx;
    int j = idx[r * PLY + t];
    const float* src = enc + ((size_t)((r % KW) * BSZn + r / KW) * PLY + j) * 512;
    for (int e = tid; e < 512; e += 256) {
        size_t o = (size_t)row * 512 + e;
        ushort a, b, c; split3(src[e], &a, &b, &c);
        x0_[o] = a; x1_[o] = b; x2_[o] = c;
    }
}

// ---- fused gates+q MFMA, kb-outer / 6-pass-inner ----
// bn<16: gates (N cols bn*128, K=1024, x|h). bn>=16: q (cols (bn-16)*128, K=512, h only).
// LDS: 6 planes (A0..2, B0..2) x 128 rows x 64B, staged ONCE per kb; 6 split
// products run from LDS (A-plane frags reused across its B partners).
// Frag addressing identical to R9 (verified absmax 0.03125, argmax exact).
// R6 lesson: no 2nd __launch_bounds__ arg (VGPR cap -> spill storm).
__global__ __launch_bounds__(256) void gates_mfma(
    const ushort* __restrict__ xs0, const ushort* __restrict__ xs1, const ushort* __restrict__ xs2,
    const ushort* __restrict__ hi0, const ushort* __restrict__ hi1, const ushort* __restrict__ hi2,
    const ushort* __restrict__ Wg0, const ushort* __restrict__ Wg1, const ushort* __restrict__ Wg2,
    const ushort* __restrict__ Wq0, const ushort* __restrict__ Wq1, const ushort* __restrict__ Wq2,
    const float* __restrict__ biasG, const float* __restrict__ bq,
    float* __restrict__ cst,
    ushort* __restrict__ ho0, ushort* __restrict__ ho1, ushort* __restrict__ ho2,
    float* __restrict__ Q2, int t, int bn_off)
{
    __shared__ uint4 ldsbuf[3072];            // 48 KB = 6 planes x 8 KB
    ushort* lds = (ushort*)ldsbuf;            // plane p: [p*4096 + row*32 + e]
    int tid = threadIdx.x;
    int bm = blockIdx.x, bn = blockIdx.y + bn_off;
    bool isg = bn < 16;
    int w = tid >> 6, lane = tid & 63;
    int wr = w >> 1, wc = w & 1;
    int r0 = bm * 128;
    int row0 = tid >> 2, row1 = row0 + 64, cch = tid & 3;

    const ushort* Ax[3] = {xs0, xs1, xs2};
    const ushort* Ah[3] = {hi0, hi1, hi2};
    const ushort* Bp[3];
    int kstart;
    size_t boff0, boff1;
    if (isg) {
        kstart = 0;
        Bp[0] = Wg0; Bp[1] = Wg1; Bp[2] = Wg2;
        boff0 = (size_t)(bn * 128 + row0) * 1024 + cch * 8;
        boff1 = (size_t)(bn * 128 + row1) * 1024 + cch * 8;
    } else {
        kstart = 16;
        Bp[0] = Wq0; Bp[1] = Wq1; Bp[2] = Wq2;
        boff0 = (size_t)((bn - 16) * 128 + row0) * 512 + cch * 8;
        boff1 = (size_t)((bn - 16) * 128 + row1) * 512 + cch * 8;
    }
    size_t aoff0 = (size_t)(r0 + row0) * 512 + cch * 8;
    size_t aoff1 = (size_t)(r0 + row1) * 512 + cch * 8;

    f32x4 acc[4][4];
    #pragma unroll
    for (int i = 0; i < 4; ++i)
        #pragma unroll
        for (int j = 0; j < 4; ++j) acc[i][j] = (f32x4){0.f, 0.f, 0.f, 0.f};

    uint4 sA[3][2], sB[3][2];
    #define LOADK(kb_) do {                                                     \
        int kloc_ = ((kb_) & 15) * 32;                                          \
        bool usex_ = isg && (kb_) < 16;                                         \
        int bk_ = isg ? (kb_) * 32 : ((kb_) - 16) * 32;                         \
        _Pragma("unroll")                                                       \
        for (int p_ = 0; p_ < 3; ++p_) {                                        \
            const ushort* ap_ = usex_ ? Ax[p_] : Ah[p_];                        \
            sA[p_][0] = *(const uint4*)(ap_ + aoff0 + kloc_);                   \
            sA[p_][1] = *(const uint4*)(ap_ + aoff1 + kloc_);                   \
            sB[p_][0] = *(const uint4*)(Bp[p_] + boff0 + bk_);                  \
            sB[p_][1] = *(const uint4*)(Bp[p_] + boff1 + bk_);                  \
        }                                                                        \
    } while (0)

    LOADK(kstart);
    for (int kb = kstart; kb < 32; ++kb) {
        __syncthreads();                      // prev iteration frag reads done
        #pragma unroll
        for (int p = 0; p < 3; ++p) {
            *(uint4*)&lds[(size_t)p * 4096 + row0 * 32 + cch * 8]       = sA[p][0];
            *(uint4*)&lds[(size_t)p * 4096 + row1 * 32 + cch * 8]       = sA[p][1];
            *(uint4*)&lds[(size_t)(3 + p) * 4096 + row0 * 32 + cch * 8] = sB[p][0];
            *(uint4*)&lds[(size_t)(3 + p) * 4096 + row1 * 32 + cch * 8] = sB[p][1];
        }
        __syncthreads();
        if (kb + 1 < 32) LOADK(kb + 1);       // prefetch hides under MFMAs
        #pragma unroll
        for (int a = 0; a < 3; ++a) {
            short8v af[4];
            #pragma unroll
            for (int fm = 0; fm < 4; ++fm)
                af[fm] = *(const short8v*)&lds[(size_t)a * 4096 +
                           (wr * 64 + fm * 16 + (lane & 15)) * 32 + (lane >> 4) * 8];
            const int nb = (a == 0) ? 3 : (a == 1) ? 2 : 1;
            #pragma unroll
            for (int b = 0; b < nb; ++b) {
                short8v bf[4];
                #pragma unroll
                for (int fn = 0; fn < 4; ++fn)
                    bf[fn] = *(const short8v*)&lds[(size_t)(3 + b) * 4096 +
                               (wc * 64 + fn * 16 + (lane & 15)) * 32 + (lane >> 4) * 8];
                #pragma unroll
                for (int fm = 0; fm < 4; ++fm)
                    #pragma unroll
                    for (int fn = 0; fn < 4; ++fn)
                        acc[fm][fn] = __builtin_amdgcn_mfma_f32_16x16x32_bf16(
                            af[fm], bf[fn], acc[fm][fn], 0, 0, 0);
            }
        }
    }

    if (isg) {
        // LSTM epilogue (R9-proven): frag fn == gate; unit u fixed per lane.
        int u = (bn * 2 + wc) * 16 + (lane & 15);
        float bI = biasG[u], bF = biasG[512 + u], bG = biasG[1024 + u], bO = biasG[1536 + u];
        #pragma unroll
        for (int fm = 0; fm < 4; ++fm) {
            #pragma unroll
            for (int reg = 0; reg < 4; ++reg) {
                int row = r0 + wr * 64 + fm * 16 + (lane >> 4) * 4 + reg;
                float gi = acc[fm][0][reg] + bI;
                float gf = acc[fm][1][reg] + bF;
                float gg = acc[fm][2][reg] + bG;
                float go = acc[fm][3][reg] + bO;
                size_t ci = (size_t)row * 512 + u;
                float c = cst[ci];
                c = sigmoidf_(gf) * c + sigmoidf_(gi) * tanhf(gg);
                float h = sigmoidf_(go) * tanhf(c);
                cst[ci] = c;
                ushort s0, s1, s2; split3(h, &s0, &s1, &s2);
                ho0[ci] = s0; ho1[ci] = s1; ho2[ci] = s2;
            }
        }
    } else {
        // q epilogue -> Q2 slot (t-1)&1 == (t+1)&1
        int slot = (t + 1) & 1;
        #pragma unroll
        for (int fn = 0; fn < 4; ++fn) {
            int col = (bn - 16) * 128 + wc * 64 + fn * 16 + (lane & 15);
            float bqv = bq[col];
            #pragma unroll
            for (int fm = 0; fm < 4; ++fm)
                #pragma unroll
                for (int reg = 0; reg < 4; ++reg) {
                    int row = r0 + wr * 64 + fm * 16 + (lane >> 4) * 4 + reg;
                    Q2[((size_t)slot * RTOT + row) * 512 + col] = acc[fm][fn][reg] + bqv;
                }
        }
    }
}

// ---- ctx = enc @ Wc^T, f32 (R1-proven kernel) ----
#define BM 128
#define BN 128
#define BKK 16
__global__ __launch_bounds__(256) void gemm_ctx(
    const float* __restrict__ A0, const float* __restrict__ A1, const float* __restrict__ A2,
    const float* __restrict__ B, float* __restrict__ C)
{
    __shared__ float As[BKK][BM + 4];
    __shared__ float Bs[BKK][BN + 4];
    int bm = blockIdx.x, bn = blockIdx.y;
    int tid = threadIdx.x;
    int tm = tid >> 4, tn = tid & 15;
    int lrow = tid >> 2, lc4 = tid & 3;

    int R0 = bm * BM;
    int tau = R0 / (BROWS * PLY);
    const float* enc = (tau == 0) ? A0 : (tau == 1) ? A1 : A2;
    int R = R0 + lrow;
    int rr = R % (BROWS * PLY); int r = rr >> 5; int p = rr & 31;
    const float* a_src0 = enc + (((size_t)((r % KW) * BSZn + r / KW)) * PLY + p) * 512;
    R = R0 + lrow + 64;
    rr = R % (BROWS * PLY); r = rr >> 5; p = rr & 31;
    const float* a_src1 = enc + (((size_t)((r % KW) * BSZn + r / KW)) * PLY + p) * 512;
    const float* b_src0 = B + (size_t)(bn * BN + lrow) * 512;
    const float* b_src1 = b_src0 + (size_t)64 * 512;

    float acc[8][8];
    #pragma unroll
    for (int i = 0; i < 8; ++i)
        #pragma unroll
        for (int j = 0; j < 8; ++j) acc[i][j] = 0.0f;

    float4 a0 = *(const float4*)(a_src0 + lc4 * 4);
    float4 a1 = *(const float4*)(a_src1 + lc4 * 4);
    float4 b0 = *(const float4*)(b_src0 + lc4 * 4);
    float4 b1 = *(const float4*)(b_src1 + lc4 * 4);

    for (int t = 0; t < 512 / BKK; ++t) {
        __syncthreads();
        As[lc4 * 4 + 0][lrow] = a0.x; As[lc4 * 4 + 1][lrow] = a0.y;
        As[lc4 * 4 + 2][lrow] = a0.z; As[lc4 * 4 + 3][lrow] = a0.w;
        As[lc4 * 4 + 0][lrow + 64] = a1.x; As[lc4 * 4 + 1][lrow + 64] = a1.y;
        As[lc4 * 4 + 2][lrow + 64] = a1.z; As[lc4 * 4 + 3][lrow + 64] = a1.w;
        Bs[lc4 * 4 + 0][lrow] = b0.x; Bs[lc4 * 4 + 1][lrow] = b0.y;
        Bs[lc4 * 4 + 2][lrow] = b0.z; Bs[lc4 * 4 + 3][lrow] = b0.w;
        Bs[lc4 * 4 + 0][lrow + 64] = b1.x; Bs[lc4 * 4 + 1][lrow + 64] = b1.y;
        Bs[lc4 * 4 + 2][lrow + 64] = b1.z; Bs[lc4 * 4 + 3][lrow + 64] = b1.w;
        __syncthreads();
        if (t + 1 < 512 / BKK) {
            int k0 = (t + 1) * BKK + lc4 * 4;
            a0 = *(const float4*)(a_src0 + k0);
            a1 = *(const float4*)(a_src1 + k0);
            b0 = *(const float4*)(b_src0 + k0);
            b1 = *(const float4*)(b_src1 + k0);
        }
        #pragma unroll
        for (int k = 0; k < BKK; ++k) {
            float af[8], bf[8];
            *(float4*)&af[0] = *(const float4*)&As[k][tm * 8];
            *(float4*)&af[4] = *(const float4*)&As[k][tm * 8 + 4];
            *(float4*)&bf[0] = *(const float4*)&Bs[k][tn * 8];
            *(float4*)&bf[4] = *(const float4*)&Bs[k][tn * 8 + 4];
            #pragma unroll
            for (int i = 0; i < 8; ++i)
                #pragma unroll
                for (int j = 0; j < 8; ++j)
                    acc[i][j] = fmaf(af[i], bf[j], acc[i][j]);
        }
    }
    int row0 = bm * BM + tm * 8;
    int col0 = bn * BN + tn * 8;
    #pragma unroll
    for (int i = 0; i < 8; ++i) {
        float* cr = C + (size_t)(row0 + i) * 512 + col0;
        float4 o0, o1;
        o0.x = acc[i][0]; o0.y = acc[i][1]; o0.z = acc[i][2]; o0.w = acc[i][3];
        o1.x = acc[i][4]; o1.y = acc[i][5]; o1.z = acc[i][6]; o1.w = acc[i][7];
        *(float4*)cr = o0;
        *(float4*)(cr + 4) = o1;
    }
}

// ---- attention, 2 steps with ctx reuse: wave w covers p in [w*8, w*8+8),
// ---- scoring BOTH steps from one ctx load. ----
__global__ __launch_bounds__(256) void attn2r(
    const float* __restrict__ Q2, const float* __restrict__ ctx,
    const float* __restrict__ vvec, float* __restrict__ out, int tbase)
{
    int row = blockIdx.x, tid = threadIdx.x;
    int w = tid >> 6, lane = tid & 63;
    __shared__ float scs[2][PLY];

    const float* q0 = Q2 + (size_t)row * 512 + lane * 8;                 // slot 0 (even step)
    const float* q1 = Q2 + ((size_t)RTOT + row) * 512 + lane * 8;        // slot 1
    const float* ctxr = ctx + (size_t)row * PLY * 512 + lane * 8;
    float qa[8], qb[8], vv[8];
    *(float4*)&qa[0] = *(const float4*)(q0);
    *(float4*)&qa[4] = *(const float4*)(q0 + 4);
    *(float4*)&qb[0] = *(const float4*)(q1);
    *(float4*)&qb[4] = *(const float4*)(q1 + 4);
    *(float4*)&vv[0] = *(const float4*)(vvec + lane * 8);
    *(float4*)&vv[4] = *(const float4*)(vvec + lane * 8 + 4);

    for (int pp = 0; pp < 8; ++pp) {
        int p = w * 8 + pp;
        const float* cp = ctxr + (size_t)p * 512;
        float cv[8];
        *(float4*)&cv[0] = *(const float4*)(cp);
        *(float4*)&cv[4] = *(const float4*)(cp + 4);
        float a0 = 0.0f, a1 = 0.0f;
        #pragma unroll
        for (int j = 0; j < 8; ++j) {
            a0 += tanhf(qa[j] + cv[j]) * vv[j];
            a1 += tanhf(qb[j] + cv[j]) * vv[j];
        }
        #pragma unroll
        for (int off = 1; off < 64; off <<= 1) {
            a0 += __shfl_xor(a0, off);
            a1 += __shfl_xor(a1, off);
        }
        if (lane == 0) { scs[0][p] = a0; scs[1][p] = a1; }
    }
    __syncthreads();

    if (tid < 64) {
        int w2 = tid >> 5, l = tid & 31;
        float x = scs[w2][l];
        float bvv = x; int bi = l;
        #pragma unroll
        for (int off = 1; off < 32; off <<= 1) {
            float ov = __shfl_xor(bvv, off, 32);
            int oi = __shfl_xor(bi, off, 32);
            if (ov > bvv || (ov == bvv && oi < bi)) { bvv = ov; bi = oi; }
        }
        float s = expf(x - bvv);
        #pragma unroll
        for (int off = 1; off < 32; off <<= 1) s += __shfl_xor(s, off, 32);
        float lse = logf(s);
        int t = tbase + w2;
        int tau = row / BROWS, r = row % BROWS;
        out[(size_t)tau * (BROWS * 1024) + (size_t)r * 1024 + t * 32 + l] = x - bvv - lse;
        if (l == 0)
            out[(size_t)3 * (BROWS * 1024) + (size_t)tau * (BROWS * 32) + r * 32 + t] = (float)bi;
    }
}

extern "C" void kernel_launch(void* const* d_in, const int* in_sizes, int n_in,
                              void* d_out, int out_size, void* d_ws, size_t ws_size,
                              hipStream_t stream)
{
    const float* home = (const float*)d_in[0];
    const int*   hidx = (const int*)d_in[1];
    const float* vis  = (const float*)d_in[2];
    const int*   vidx = (const int*)d_in[3];
    const float* team = (const float*)d_in[4];
    const int*   tidx = (const int*)d_in[5];
    const float* init_embed = (const float*)d_in[6];
    const float* W_ih = (const float*)d_in[7];
    const float* W_hh = (const float*)d_in[8];
    const float* b_ih = (const float*)d_in[9];
    const float* b_hh = (const float*)d_in[10];
    const float* Wq   = (const float*)d_in[11];
    const float* bq   = (const float*)d_in[12];
    const float* Wc   = (const float*)d_in[13];
    const float* vvec = (const float*)d_in[14];
    float* out = (float*)d_out;
    (void)in_sizes; (void)n_in; (void)out_size; (void)ws_size;

    char* wsb = (char*)d_ws;
    float* ctx   = (float*)wsb; wsb += (size_t)RTOT * PLY * 512 * 4;   // 302.0 MB
    float* cst   = (float*)wsb; wsb += (size_t)RTOT * 512 * 4;         // 9.4 MB
    float* Q2    = (float*)wsb; wsb += (size_t)2 * RTOT * 512 * 4;     // 18.9 MB
    float* biasG = (float*)wsb; wsb += 2048 * 4;
    ushort* Wg[3], *Wq3[3], *xs[3], *hs[2][3];
    for (int i = 0; i < 3; ++i) { Wg[i]  = (ushort*)wsb; wsb += (size_t)2048 * 1024 * 2; }
    for (int i = 0; i < 3; ++i) { Wq3[i] = (ushort*)wsb; wsb += (size_t)512 * 512 * 2; }
    for (int i = 0; i < 3; ++i) { xs[i]  = (ushort*)wsb; wsb += (size_t)RTOT * 512 * 2; }
    for (int b = 0; b < 2; ++b)
        for (int i = 0; i < 3; ++i) { hs[b][i] = (ushort*)wsb; wsb += (size_t)RTOT * 512 * 2; }
    // total ~386.9 MB (fits; proven in R9)

    prep_split<<<2560, 256, 0, stream>>>(W_ih, W_hh, Wq, b_ih, b_hh,
                                         Wg[0], Wg[1], Wg[2], Wq3[0], Wq3[1], Wq3[2], biasG);
    initsplit<<<RTOT, 256, 0, stream>>>(home, vis, team, init_embed, cst,
                                        hs[1][0], hs[1][1], hs[1][2],
                                        xs[0], xs[1], xs[2]);
    gemm_ctx<<<dim3(RTOT * PLY / BM, 512 / BN), 256, 0, stream>>>(home, vis, team, Wc, ctx);

    for (int t = 0; t < 32; ++t) {
        int hin = (t + 1) & 1, hout = t & 1;
        gates_mfma<<<dim3(36, 20), 256, 0, stream>>>(
            xs[0], xs[1], xs[2],
            hs[hin][0], hs[hin][1], hs[hin][2],
            Wg[0], Wg[1], Wg[2], Wq3[0], Wq3[1], Wq3[2],
            biasG, bq, cst,
            hs[hout][0], hs[hout][1], hs[hout][2],
            Q2, t, 0);
        if (t < 31)
            xprep<<<RTOT, 256, 0, stream>>>(home, vis, team, hidx, vidx, tidx,
                                            xs[0], xs[1], xs[2], t);
        if (t >= 2 && (t & 1) == 0)
            attn2r<<<RTOT, 256, 0, stream>>>(Q2, ctx, vvec, out, t - 2);
    }
    // tail: q31 from h31 (hs[1]); q-only blocks (bn_off=16), t=32 -> slot 1
    gates_mfma<<<dim3(36, 4), 256, 0, stream>>>(
        xs[0], xs[1], xs[2],
        hs[1][0], hs[1][1], hs[1][2],
        Wg[0], Wg[1], Wg[2], Wq3[0], Wq3[1], Wq3[2],
        biasG, bq, cst,
        hs[0][0], hs[0][1], hs[0][2],
        Q2, 32, 16);
    attn2r<<<RTOT, 256, 0, stream>>>(Q2, ctx, vvec, out, 30);
}

// Round 11
// 13122.342 us; speedup vs baseline: 1.4813x; 1.4813x over previous
//
#include <hip/hip_runtime.h>
#include <hip/hip_bf16.h>
#include <math.h>

#define KW 24
#define BSZn 64
#define PLY 32
#define BROWS 1536            // BSZ*KW rows per task
#define RTOT 4608             // 3*BROWS

typedef __attribute__((ext_vector_type(8))) short short8v;  // 8 bf16 (4 VGPRs)
typedef __attribute__((ext_vector_type(4))) float f32x4;

__device__ __forceinline__ float sigmoidf_(float x) { return 1.0f / (1.0f + expf(-x)); }

// exact 3-way bf16 split: v = s0 + s1 + s2 + O(2^-26 v)
__device__ __forceinline__ void split3(float v, ushort* a, ushort* b, ushort* c)
{
    __hip_bfloat16 h1 = __float2bfloat16(v);  float f1 = __bfloat162float(h1);
    float r1 = v - f1;
    __hip_bfloat16 h2 = __float2bfloat16(r1); float f2 = __bfloat162float(h2);
    float r2 = r1 - f2;
    __hip_bfloat16 h3 = __float2bfloat16(r2);
    *a = *(ushort*)&h1; *b = *(ushort*)&h2; *c = *(ushort*)&h3;
}

// ---- weights prep (R9-proven) ----
// Gate cols: n = ublk*64 + gate*16 + ui ; source row = gate*512 + ublk*16 + ui.
__global__ void prep_split(const float* __restrict__ W_ih, const float* __restrict__ W_hh,
                           const float* __restrict__ Wq,
                           const float* __restrict__ b_ih, const float* __restrict__ b_hh,
                           ushort* __restrict__ Wg0, ushort* __restrict__ Wg1, ushort* __restrict__ Wg2,
                           ushort* __restrict__ Wq0, ushort* __restrict__ Wq1, ushort* __restrict__ Wq2,
                           float* __restrict__ biasG)
{
    int n = blockIdx.x, tid = threadIdx.x;     // 0..2559
    if (n < 2048) {
        int ublk = n >> 6, gate = (n >> 4) & 3, ui = n & 15;
        int src = gate * 512 + ublk * 16 + ui;
        for (int k = tid; k < 1024; k += 256) {
            float v = (k < 512) ? W_ih[(size_t)src * 512 + k]
                                : W_hh[(size_t)src * 512 + (k - 512)];
            ushort s0, s1, s2; split3(v, &s0, &s1, &s2);
            Wg0[(size_t)n * 1024 + k] = s0;
            Wg1[(size_t)n * 1024 + k] = s1;
            Wg2[(size_t)n * 1024 + k] = s2;
        }
        if (tid == 0) biasG[src] = b_ih[src] + b_hh[src];
    } else {
        int n2 = n - 2048;
        for (int k = tid; k < 512; k += 256) {
            ushort s0, s1, s2; split3(Wq[(size_t)n2 * 512 + k], &s0, &s1, &s2);
            Wq0[(size_t)n2 * 512 + k] = s0;
            Wq1[(size_t)n2 * 512 + k] = s1;
            Wq2[(size_t)n2 * 512 + k] = s2;
        }
    }
}

// ---- init (R9-proven): cst = h0; hs[1] = split(h0); xs = split(init_embed) ----
__global__ void initsplit(const float* __restrict__ home, const float* __restrict__ vis,
                          const float* __restrict__ team, const float* __restrict__ init_embed,
                          float* __restrict__ cst,
                          ushort* __restrict__ h0_, ushort* __restrict__ h1_, ushort* __restrict__ h2_,
                          ushort* __restrict__ x0_, ushort* __restrict__ x1_, ushort* __restrict__ x2_)
{
    int row = blockIdx.x, tid = threadIdx.x;
    int tau = row / BROWS, r = row % BROWS;
    const float* enc = (tau == 0) ? home : (tau == 1) ? vis : team;
    const float* base = enc + ((size_t)((r % KW) * BSZn + r / KW) * PLY) * 512;
    for (int e = tid; e < 512; e += 256) {
        float s = 0.0f;
        for (int p = 0; p < PLY; ++p) s += base[(size_t)p * 512 + e];
        size_t o = (size_t)row * 512 + e;
        cst[o] = s;
        ushort a, b, c;
        split3(s, &a, &b, &c);
        h0_[o] = a; h1_[o] = b; h2_[o] = c;
        split3(init_embed[e], &a, &b, &c);
        x0_[o] = a; x1_[o] = b; x2_[o] = c;
    }
}

// ---- gates MFMA: R9 pass-outer structure + R11 register prefetch ----
// 128x128 block, 4 waves (2x2 of 64x64), 16x16x32 bf16, BK=32, 16KB LDS.
// R6 lesson: no 2nd __launch_bounds__ arg (VGPR cap -> spill storm).
__global__ __launch_bounds__(256) void gates_mfma(
    const ushort* __restrict__ x0_, const ushort* __restrict__ x1_, const ushort* __restrict__ x2_,
    const ushort* __restrict__ hi0, const ushort* __restrict__ hi1, const ushort* __restrict__ hi2,
    const ushort* __restrict__ Wg0, const ushort* __restrict__ Wg1, const ushort* __restrict__ Wg2,
    const float* __restrict__ biasG, float* __restrict__ cst,
    ushort* __restrict__ ho0, ushort* __restrict__ ho1, ushort* __restrict__ ho2)
{
    __shared__ float4 LdsBuf[1024];           // 16 KB: A tile [0,8K), B tile [8K,16K)
    char* LdsA = (char*)LdsBuf;
    char* LdsB = LdsA + 8192;
    int tid = threadIdx.x;
    int bm = blockIdx.x, bn = blockIdx.y;
    int w = tid >> 6, lane = tid & 63;
    int wr = w >> 1, wc = w & 1;
    int r0 = bm * 128;
    int nbase = bn * 128;
    int srow = tid >> 1, sh = tid & 1;        // stager: row 0..127, 32B half

    const ushort* Ax[3] = {x0_, x1_, x2_};
    const ushort* Ah[3] = {hi0, hi1, hi2};
    const ushort* Bg[3] = {Wg0, Wg1, Wg2};
    const int pa[6] = {0, 2, 1, 0, 1, 0};     // smallest products first
    const int pb[6] = {2, 0, 1, 1, 0, 0};

    f32x4 acc[4][4];
    #pragma unroll
    for (int i = 0; i < 4; ++i)
        #pragma unroll
        for (int j = 0; j < 4; ++j) acc[i][j] = (f32x4){0.f, 0.f, 0.f, 0.f};

    uint4 sa0, sa1, sb0, sb1;
    #pragma unroll
    for (int p = 0; p < 6; ++p) {
        const ushort* Axp = Ax[pa[p]];
        const ushort* Ahp = Ah[pa[p]];
        const ushort* Bb  = Bg[pb[p]] + (size_t)nbase * 1024;
        // pass prologue: load kb=0 (x half)
        {
            const ushort* as = Axp + (size_t)(r0 + srow) * 512 + sh * 16;
            sa0 = *(const uint4*)as;
            sa1 = *(const uint4*)(as + 8);
            const ushort* bs = Bb + (size_t)srow * 1024 + sh * 16;
            sb0 = *(const uint4*)bs;
            sb1 = *(const uint4*)(bs + 8);
        }
        for (int kb = 0; kb < 32; ++kb) {
            __syncthreads();                  // prev iteration's frag reads done
            *(uint4*)(LdsA + srow * 64 + sh * 32)      = sa0;
            *(uint4*)(LdsA + srow * 64 + sh * 32 + 16) = sa1;
            *(uint4*)(LdsB + srow * 64 + sh * 32)      = sb0;
            *(uint4*)(LdsB + srow * 64 + sh * 32 + 16) = sb1;
            __syncthreads();
            if (kb + 1 < 32) {                // prefetch kb+1: hides under MFMAs
                int kb2 = kb + 1;
                const ushort* Abase = (kb2 < 16) ? Axp : Ahp;
                const ushort* as = Abase + (size_t)(r0 + srow) * 512 + (kb2 & 15) * 32 + sh * 16;
                sa0 = *(const uint4*)as;
                sa1 = *(const uint4*)(as + 8);
                const ushort* bs = Bb + (size_t)srow * 1024 + kb2 * 32 + sh * 16;
                sb0 = *(const uint4*)bs;
                sb1 = *(const uint4*)(bs + 8);
            }
            short8v af[4], bf[4];
            #pragma unroll
            for (int fm = 0; fm < 4; ++fm)
                af[fm] = *(const short8v*)(LdsA + (wr * 64 + fm * 16 + (lane & 15)) * 64 + (lane >> 4) * 16);
            #pragma unroll
            for (int fn = 0; fn < 4; ++fn)
                bf[fn] = *(const short8v*)(LdsB + (wc * 64 + fn * 16 + (lane & 15)) * 64 + (lane >> 4) * 16);
            #pragma unroll
            for (int fm = 0; fm < 4; ++fm)
                #pragma unroll
                for (int fn = 0; fn < 4; ++fn)
                    acc[fm][fn] = __builtin_amdgcn_mfma_f32_16x16x32_bf16(
                        af[fm], bf[fn], acc[fm][fn], 0, 0, 0);
        }
    }

    // LSTM epilogue (R9-proven): frag fn == gate; unit u fixed per lane.
    int u = (bn * 2 + wc) * 16 + (lane & 15);
    float bI = biasG[u], bF = biasG[512 + u], bG = biasG[1024 + u], bO = biasG[1536 + u];
    #pragma unroll
    for (int fm = 0; fm < 4; ++fm) {
        #pragma unroll
        for (int reg = 0; reg < 4; ++reg) {
            int row = r0 + wr * 64 + fm * 16 + (lane >> 4) * 4 + reg;
            float gi = acc[fm][0][reg] + bI;
            float gf = acc[fm][1][reg] + bF;
            float gg = acc[fm][2][reg] + bG;
            float go = acc[fm][3][reg] + bO;
            size_t ci = (size_t)row * 512 + u;
            float c = cst[ci];
            c = sigmoidf_(gf) * c + sigmoidf_(gi) * tanhf(gg);
            float h = sigmoidf_(go) * tanhf(c);
            cst[ci] = c;
            ushort s0, s1, s2; split3(h, &s0, &s1, &s2);
            ho0[ci] = s0; ho1[ci] = s1; ho2[ci] = s2;
        }
    }
}

// ---- fused q MFMA + x-gather/split launch ----
// bid < 144: q = h @ Wq^T + bq (R9 q_mfma + prefetch), 36 bm x 4 bn.
// bid >= 144: xprep row (bid-144) for step t (concurrent, fills idle CUs).
__global__ __launch_bounds__(256) void qx_k(
    const ushort* __restrict__ hi0, const ushort* __restrict__ hi1, const ushort* __restrict__ hi2,
    const ushort* __restrict__ Wq0, const ushort* __restrict__ Wq1, const ushort* __restrict__ Wq2,
    const float* __restrict__ bq, float* __restrict__ Qout,
    const float* __restrict__ home, const float* __restrict__ vis, const float* __restrict__ team,
    const int* __restrict__ hidx, const int* __restrict__ vidx, const int* __restrict__ tidx,
    ushort* __restrict__ x0_, ushort* __restrict__ x1_, ushort* __restrict__ x2_, int t)
{
    __shared__ float4 LdsBuf[1024];
    int bid = blockIdx.x, tid = threadIdx.x;
    if (bid >= 144) {
        // ---------------- xprep: gather x_{t+1} row and split ----------------
        int row = bid - 144;
        int tau = row / BROWS, r = row % BROWS;
        const float* enc = (tau == 0) ? home : (tau == 1) ? vis : team;
        const int* idx = (tau == 0) ? hidx : (tau == 1) ? vidx : tidx;
        int j = idx[r * PLY + t];
        const float* src = enc + ((size_t)((r % KW) * BSZn + r / KW) * PLY + j) * 512;
        for (int e = tid; e < 512; e += 256) {
            size_t o = (size_t)row * 512 + e;
            ushort a, b, c; split3(src[e], &a, &b, &c);
            x0_[o] = a; x1_[o] = b; x2_[o] = c;
        }
        return;
    }
    // ---------------- q MFMA ----------------
    char* LdsA = (char*)LdsBuf;
    char* LdsB = LdsA + 8192;
    int bm = bid >> 2, bn = bid & 3;
    int w = tid >> 6, lane = tid & 63;
    int wr = w >> 1, wc = w & 1;
    int r0 = bm * 128;
    int nbase = bn * 128;
    int srow = tid >> 1, sh = tid & 1;

    const ushort* Ah[3] = {hi0, hi1, hi2};
    const ushort* Bg[3] = {Wq0, Wq1, Wq2};
    const int pa[6] = {0, 2, 1, 0, 1, 0};
    const int pb[6] = {2, 0, 1, 1, 0, 0};

    f32x4 acc[4][4];
    #pragma unroll
    for (int i = 0; i < 4; ++i)
        #pragma unroll
        for (int j = 0; j < 4; ++j) acc[i][j] = (f32x4){0.f, 0.f, 0.f, 0.f};

    uint4 sa0, sa1, sb0, sb1;
    #pragma unroll
    for (int p = 0; p < 6; ++p) {
        const ushort* Ap = Ah[pa[p]];
        const ushort* Bb = Bg[pb[p]] + (size_t)nbase * 512;
        {
            const ushort* as = Ap + (size_t)(r0 + srow) * 512 + sh * 16;
            sa0 = *(const uint4*)as;
            sa1 = *(const uint4*)(as + 8);
            const ushort* bs = Bb + (size_t)srow * 512 + sh * 16;
            sb0 = *(const uint4*)bs;
            sb1 = *(const uint4*)(bs + 8);
        }
        for (int kb = 0; kb < 16; ++kb) {
            __syncthreads();
            *(uint4*)(LdsA + srow * 64 + sh * 32)      = sa0;
            *(uint4*)(LdsA + srow * 64 + sh * 32 + 16) = sa1;
            *(uint4*)(LdsB + srow * 64 + sh * 32)      = sb0;
            *(uint4*)(LdsB + srow * 64 + sh * 32 + 16) = sb1;
            __syncthreads();
            if (kb + 1 < 16) {
                int kb2 = kb + 1;
                const ushort* as = Ap + (size_t)(r0 + srow) * 512 + kb2 * 32 + sh * 16;
                sa0 = *(const uint4*)as;
                sa1 = *(const uint4*)(as + 8);
                const ushort* bs = Bb + (size_t)srow * 512 + kb2 * 32 + sh * 16;
                sb0 = *(const uint4*)bs;
                sb1 = *(const uint4*)(bs + 8);
            }
            short8v af[4], bf[4];
            #pragma unroll
            for (int fm = 0; fm < 4; ++fm)
                af[fm] = *(const short8v*)(LdsA + (wr * 64 + fm * 16 + (lane & 15)) * 64 + (lane >> 4) * 16);
            #pragma unroll
            for (int fn = 0; fn < 4; ++fn)
                bf[fn] = *(const short8v*)(LdsB + (wc * 64 + fn * 16 + (lane & 15)) * 64 + (lane >> 4) * 16);
            #pragma unroll
            for (int fm = 0; fm < 4; ++fm)
                #pragma unroll
                for (int fn = 0; fn < 4; ++fn)
                    acc[fm][fn] = __builtin_amdgcn_mfma_f32_16x16x32_bf16(
                        af[fm], bf[fn], acc[fm][fn], 0, 0, 0);
        }
    }

    #pragma unroll
    for (int fn = 0; fn < 4; ++fn) {
        int col = nbase + wc * 64 + fn * 16 + (lane & 15);
        float bqv = bq[col];
        #pragma unroll
        for (int fm = 0; fm < 4; ++fm)
            #pragma unroll
            for (int reg = 0; reg < 4; ++reg) {
                int row = r0 + wr * 64 + fm * 16 + (lane >> 4) * 4 + reg;
                Qout[(size_t)row * 512 + col] = acc[fm][fn][reg] + bqv;
            }
    }
}

// ---- ctx = enc @ Wc^T, f32 (R1-proven kernel) ----
#define BM 128
#define BN 128
#define BKK 16
__global__ __launch_bounds__(256) void gemm_ctx(
    const float* __restrict__ A0, const float* __restrict__ A1, const float* __restrict__ A2,
    const float* __restrict__ B, float* __restrict__ C)
{
    __shared__ float As[BKK][BM + 4];
    __shared__ float Bs[BKK][BN + 4];
    int bm = blockIdx.x, bn = blockIdx.y;
    int tid = threadIdx.x;
    int tm = tid >> 4, tn = tid & 15;
    int lrow = tid >> 2, lc4 = tid & 3;

    int R0 = bm * BM;
    int tau = R0 / (BROWS * PLY);
    const float* enc = (tau == 0) ? A0 : (tau == 1) ? A1 : A2;
    int R = R0 + lrow;
    int rr = R % (BROWS * PLY); int r = rr >> 5; int p = rr & 31;
    const float* a_src0 = enc + (((size_t)((r % KW) * BSZn + r / KW)) * PLY + p) * 512;
    R = R0 + lrow + 64;
    rr = R % (BROWS * PLY); r = rr >> 5; p = rr & 31;
    const float* a_src1 = enc + (((size_t)((r % KW) * BSZn + r / KW)) * PLY + p) * 512;
    const float* b_src0 = B + (size_t)(bn * BN + lrow) * 512;
    const float* b_src1 = b_src0 + (size_t)64 * 512;

    float acc[8][8];
    #pragma unroll
    for (int i = 0; i < 8; ++i)
        #pragma unroll
        for (int j = 0; j < 8; ++j) acc[i][j] = 0.0f;

    float4 a0 = *(const float4*)(a_src0 + lc4 * 4);
    float4 a1 = *(const float4*)(a_src1 + lc4 * 4);
    float4 b0 = *(const float4*)(b_src0 + lc4 * 4);
    float4 b1 = *(const float4*)(b_src1 + lc4 * 4);

    for (int t = 0; t < 512 / BKK; ++t) {
        __syncthreads();
        As[lc4 * 4 + 0][lrow] = a0.x; As[lc4 * 4 + 1][lrow] = a0.y;
        As[lc4 * 4 + 2][lrow] = a0.z; As[lc4 * 4 + 3][lrow] = a0.w;
        As[lc4 * 4 + 0][lrow + 64] = a1.x; As[lc4 * 4 + 1][lrow + 64] = a1.y;
        As[lc4 * 4 + 2][lrow + 64] = a1.z; As[lc4 * 4 + 3][lrow + 64] = a1.w;
        Bs[lc4 * 4 + 0][lrow] = b0.x; Bs[lc4 * 4 + 1][lrow] = b0.y;
        Bs[lc4 * 4 + 2][lrow] = b0.z; Bs[lc4 * 4 + 3][lrow] = b0.w;
        Bs[lc4 * 4 + 0][lrow + 64] = b1.x; Bs[lc4 * 4 + 1][lrow + 64] = b1.y;
        Bs[lc4 * 4 + 2][lrow + 64] = b1.z; Bs[lc4 * 4 + 3][lrow + 64] = b1.w;
        __syncthreads();
        if (t + 1 < 512 / BKK) {
            int k0 = (t + 1) * BKK + lc4 * 4;
            a0 = *(const float4*)(a_src0 + k0);
            a1 = *(const float4*)(a_src1 + k0);
            b0 = *(const float4*)(b_src0 + k0);
            b1 = *(const float4*)(b_src1 + k0);
        }
        #pragma unroll
        for (int k = 0; k < BKK; ++k) {
            float af[8], bf[8];
            *(float4*)&af[0] = *(const float4*)&As[k][tm * 8];
            *(float4*)&af[4] = *(const float4*)&As[k][tm * 8 + 4];
            *(float4*)&bf[0] = *(const float4*)&Bs[k][tn * 8];
            *(float4*)&bf[4] = *(const float4*)&Bs[k][tn * 8 + 4];
            #pragma unroll
            for (int i = 0; i < 8; ++i)
                #pragma unroll
                for (int j = 0; j < 8; ++j)
                    acc[i][j] = fmaf(af[i], bf[j], acc[i][j]);
        }
    }
    int row0 = bm * BM + tm * 8;
    int col0 = bn * BN + tn * 8;
    #pragma unroll
    for (int i = 0; i < 8; ++i) {
        float* cr = C + (size_t)(row0 + i) * 512 + col0;
        float4 o0, o1;
        o0.x = acc[i][0]; o0.y = acc[i][1]; o0.z = acc[i][2]; o0.w = acc[i][3];
        o1.x = acc[i][4]; o1.y = acc[i][5]; o1.z = acc[i][6]; o1.w = acc[i][7];
        *(float4*)cr = o0;
        *(float4*)(cr + 4) = o1;
    }
}

// ---- attention, 2 steps with ctx reuse (R10-proven): wave w covers 8 ctx rows,
// ---- scoring BOTH steps from one load. tbase even: q0=slot0, q1=slot1. ----
__global__ __launch_bounds__(256) void attn2r(
    const float* __restrict__ Q2, const float* __restrict__ ctx,
    const float* __restrict__ vvec, float* __restrict__ out, int tbase)
{
    int row = blockIdx.x, tid = threadIdx.x;
    int w = tid >> 6, lane = tid & 63;
    __shared__ float scs[2][PLY];

    const float* q0 = Q2 + (size_t)row * 512 + lane * 8;                 // slot 0 (even step)
    const float* q1 = Q2 + ((size_t)RTOT + row) * 512 + lane * 8;        // slot 1
    const float* ctxr = ctx + (size_t)row * PLY * 512 + lane * 8;
    float qa[8], qb[8], vv[8];
    *(float4*)&qa[0] = *(const float4*)(q0);
    *(float4*)&qa[4] = *(const float4*)(q0 + 4);
    *(float4*)&qb[0] = *(const float4*)(q1);
    *(float4*)&qb[4] = *(const float4*)(q1 + 4);
    *(float4*)&vv[0] = *(const float4*)(vvec + lane * 8);
    *(float4*)&vv[4] = *(const float4*)(vvec + lane * 8 + 4);

    for (int pp = 0; pp < 8; ++pp) {
        int p = w * 8 + pp;
        const float* cp = ctxr + (size_t)p * 512;
        float cv[8];
        *(float4*)&cv[0] = *(const float4*)(cp);
        *(float4*)&cv[4] = *(const float4*)(cp + 4);
        float a0 = 0.0f, a1 = 0.0f;
        #pragma unroll
        for (int j = 0; j < 8; ++j) {
            a0 += tanhf(qa[j] + cv[j]) * vv[j];
            a1 += tanhf(qb[j] + cv[j]) * vv[j];
        }
        #pragma unroll
        for (int off = 1; off < 64; off <<= 1) {
            a0 += __shfl_xor(a0, off);
            a1 += __shfl_xor(a1, off);
        }
        if (lane == 0) { scs[0][p] = a0; scs[1][p] = a1; }
    }
    __syncthreads();

    if (tid < 64) {
        int w2 = tid >> 5, l = tid & 31;
        float x = scs[w2][l];
        float bvv = x; int bi = l;
        #pragma unroll
        for (int off = 1; off < 32; off <<= 1) {
            float ov = __shfl_xor(bvv, off, 32);
            int oi = __shfl_xor(bi, off, 32);
            if (ov > bvv || (ov == bvv && oi < bi)) { bvv = ov; bi = oi; }
        }
        float s = expf(x - bvv);
        #pragma unroll
        for (int off = 1; off < 32; off <<= 1) s += __shfl_xor(s, off, 32);
        float lse = logf(s);
        int t = tbase + w2;
        int tau = row / BROWS, r = row % BROWS;
        out[(size_t)tau * (BROWS * 1024) + (size_t)r * 1024 + t * 32 + l] = x - bvv - lse;
        if (l == 0)
            out[(size_t)3 * (BROWS * 1024) + (size_t)tau * (BROWS * 32) + r * 32 + t] = (float)bi;
    }
}

extern "C" void kernel_launch(void* const* d_in, const int* in_sizes, int n_in,
                              void* d_out, int out_size, void* d_ws, size_t ws_size,
                              hipStream_t stream)
{
    const float* home = (const float*)d_in[0];
    const int*   hidx = (const int*)d_in[1];
    const float* vis  = (const float*)d_in[2];
    const int*   vidx = (const int*)d_in[3];
    const float* team = (const float*)d_in[4];
    const int*   tidx = (const int*)d_in[5];
    const float* init_embed = (const float*)d_in[6];
    const float* W_ih = (const float*)d_in[7];
    const float* W_hh = (const float*)d_in[8];
    const float* b_ih = (const float*)d_in[9];
    const float* b_hh = (const float*)d_in[10];
    const float* Wq   = (const float*)d_in[11];
    const float* bq   = (const float*)d_in[12];
    const float* Wc   = (const float*)d_in[13];
    const float* vvec = (const float*)d_in[14];
    float* out = (float*)d_out;
    (void)in_sizes; (void)n_in; (void)out_size; (void)ws_size;

    char* wsb = (char*)d_ws;
    float* ctx   = (float*)wsb; wsb += (size_t)RTOT * PLY * 512 * 4;   // 302.0 MB
    float* cst   = (float*)wsb; wsb += (size_t)RTOT * 512 * 4;         // 9.4 MB
    float* Q2    = (float*)wsb; wsb += (size_t)2 * RTOT * 512 * 4;     // 18.9 MB
    float* biasG = (float*)wsb; wsb += 2048 * 4;
    ushort* Wg[3], *Wq3[3], *xs[3], *hs[2][3];
    for (int i = 0; i < 3; ++i) { Wg[i]  = (ushort*)wsb; wsb += (size_t)2048 * 1024 * 2; }
    for (int i = 0; i < 3; ++i) { Wq3[i] = (ushort*)wsb; wsb += (size_t)512 * 512 * 2; }
    for (int i = 0; i < 3; ++i) { xs[i]  = (ushort*)wsb; wsb += (size_t)RTOT * 512 * 2; }
    for (int b = 0; b < 2; ++b)
        for (int i = 0; i < 3; ++i) { hs[b][i] = (ushort*)wsb; wsb += (size_t)RTOT * 512 * 2; }
    // total ~386.9 MB (proven fit in R9)

    prep_split<<<2560, 256, 0, stream>>>(W_ih, W_hh, Wq, b_ih, b_hh,
                                         Wg[0], Wg[1], Wg[2], Wq3[0], Wq3[1], Wq3[2], biasG);
    initsplit<<<RTOT, 256, 0, stream>>>(home, vis, team, init_embed, cst,
                                        hs[1][0], hs[1][1], hs[1][2],
                                        xs[0], xs[1], xs[2]);
    gemm_ctx<<<dim3(RTOT * PLY / BM, 512 / BN), 256, 0, stream>>>(home, vis, team, Wc, ctx);

    for (int t = 0; t < 32; ++t) {
        int hin = (t + 1) & 1, hout = t & 1;
        gates_mfma<<<dim3(36, 16), 256, 0, stream>>>(
            xs[0], xs[1], xs[2],
            hs[hin][0], hs[hin][1], hs[hin][2],
            Wg[0], Wg[1], Wg[2], biasG, cst,
            hs[hout][0], hs[hout][1], hs[hout][2]);
        // q_t -> Q2 slot t&1, plus concurrent x_{t+1} gather/split (t<31)
        int nx = (t < 31) ? RTOT : 0;
        qx_k<<<144 + nx, 256, 0, stream>>>(
            hs[hout][0], hs[hout][1], hs[hout][2],
            Wq3[0], Wq3[1], Wq3[2], bq,
            Q2 + (size_t)(t & 1) * RTOT * 512,
            home, vis, team, hidx, vidx, tidx,
            xs[0], xs[1], xs[2], t);
        if (t & 1)   // q_{t-1} (slot 0) + q_t (slot 1) ready; covers (30,31) at t=31
            attn2r<<<RTOT, 256, 0, stream>>>(Q2, ctx, vvec, out, t - 1);
    }
}

// Round 12
// 10676.942 us; speedup vs baseline: 1.8205x; 1.2290x over previous
//
#include <hip/hip_runtime.h>
#include <hip/hip_bf16.h>
#include <math.h>

#define KW 24
#define BSZn 64
#define PLY 32
#define BROWS 1536            // BSZ*KW rows per task
#define RTOT 4608             // 3*BROWS

typedef __attribute__((ext_vector_type(8))) short short8v;  // 8 bf16 (4 VGPRs)
typedef __attribute__((ext_vector_type(4))) float f32x4;

__device__ __forceinline__ float sigmoidf_(float x) { return 1.0f / (1.0f + expf(-x)); }

// exact 3-way bf16 split: v = s0 + s1 + s2 + O(2^-26 v)
__device__ __forceinline__ void split3(float v, ushort* a, ushort* b, ushort* c)
{
    __hip_bfloat16 h1 = __float2bfloat16(v);  float f1 = __bfloat162float(h1);
    float r1 = v - f1;
    __hip_bfloat16 h2 = __float2bfloat16(r1); float f2 = __bfloat162float(h2);
    float r2 = r1 - f2;
    __hip_bfloat16 h3 = __float2bfloat16(r2);
    *a = *(ushort*)&h1; *b = *(ushort*)&h2; *c = *(ushort*)&h3;
}

// ---- weights prep (R9-proven, verbatim) ----
__global__ void prep_split(const float* __restrict__ W_ih, const float* __restrict__ W_hh,
                           const float* __restrict__ Wq,
                           const float* __restrict__ b_ih, const float* __restrict__ b_hh,
                           ushort* __restrict__ Wg0, ushort* __restrict__ Wg1, ushort* __restrict__ Wg2,
                           ushort* __restrict__ Wq0, ushort* __restrict__ Wq1, ushort* __restrict__ Wq2,
                           float* __restrict__ biasG)
{
    int n = blockIdx.x, tid = threadIdx.x;     // 0..2559
    if (n < 2048) {
        int ublk = n >> 6, gate = (n >> 4) & 3, ui = n & 15;
        int src = gate * 512 + ublk * 16 + ui;
        for (int k = tid; k < 1024; k += 256) {
            float v = (k < 512) ? W_ih[(size_t)src * 512 + k]
                                : W_hh[(size_t)src * 512 + (k - 512)];
            ushort s0, s1, s2; split3(v, &s0, &s1, &s2);
            Wg0[(size_t)n * 1024 + k] = s0;
            Wg1[(size_t)n * 1024 + k] = s1;
            Wg2[(size_t)n * 1024 + k] = s2;
        }
        if (tid == 0) biasG[src] = b_ih[src] + b_hh[src];
    } else {
        int n2 = n - 2048;
        for (int k = tid; k < 512; k += 256) {
            ushort s0, s1, s2; split3(Wq[(size_t)n2 * 512 + k], &s0, &s1, &s2);
            Wq0[(size_t)n2 * 512 + k] = s0;
            Wq1[(size_t)n2 * 512 + k] = s1;
            Wq2[(size_t)n2 * 512 + k] = s2;
        }
    }
}

// ---- init (R9-proven, verbatim) ----
__global__ void initsplit(const float* __restrict__ home, const float* __restrict__ vis,
                          const float* __restrict__ team, const float* __restrict__ init_embed,
                          float* __restrict__ cst,
                          ushort* __restrict__ h0_, ushort* __restrict__ h1_, ushort* __restrict__ h2_,
                          ushort* __restrict__ x0_, ushort* __restrict__ x1_, ushort* __restrict__ x2_)
{
    int row = blockIdx.x, tid = threadIdx.x;
    int tau = row / BROWS, r = row % BROWS;
    const float* enc = (tau == 0) ? home : (tau == 1) ? vis : team;
    const float* base = enc + ((size_t)((r % KW) * BSZn + r / KW) * PLY) * 512;
    for (int e = tid; e < 512; e += 256) {
        float s = 0.0f;
        for (int p = 0; p < PLY; ++p) s += base[(size_t)p * 512 + e];
        size_t o = (size_t)row * 512 + e;
        cst[o] = s;
        ushort a, b, c;
        split3(s, &a, &b, &c);
        h0_[o] = a; h1_[o] = b; h2_[o] = c;
        split3(init_embed[e], &a, &b, &c);
        x0_[o] = a; x1_[o] = b; x2_[o] = c;
    }
}

// ---- gather x_{t+1} and split (R9-proven, verbatim) ----
__global__ void xprep(const float* __restrict__ home, const float* __restrict__ vis,
                      const float* __restrict__ team,
                      const int* __restrict__ hidx, const int* __restrict__ vidx,
                      const int* __restrict__ tidx,
                      ushort* __restrict__ x0_, ushort* __restrict__ x1_, ushort* __restrict__ x2_,
                      int t)
{
    int row = blockIdx.x, tid = threadIdx.x;
    int tau = row / BROWS, r = row % BROWS;
    const float* enc = (tau == 0) ? home : (tau == 1) ? vis : team;
    const int* idx = (tau == 0) ? hidx : (tau == 1) ? vidx : tidx;
    int j = idx[r * PLY + t];
    const float* src = enc + ((size_t)((r % KW) * BSZn + r / KW) * PLY + j) * 512;
    for (int e = tid; e < 512; e += 256) {
        size_t o = (size_t)row * 512 + e;
        ushort a, b, c; split3(src[e], &a, &b, &c);
        x0_[o] = a; x1_[o] = b; x2_[o] = c;
    }
}

// ---- gates MFMA (R9-proven, VERBATIM — no prefetch: 3 attempts at source-level
// ---- pipelining all regressed; compiler's implicit wave overlap wins) ----
__global__ __launch_bounds__(256) void gates_mfma(
    const ushort* __restrict__ x0_, const ushort* __restrict__ x1_, const ushort* __restrict__ x2_,
    const ushort* __restrict__ hi0, const ushort* __restrict__ hi1, const ushort* __restrict__ hi2,
    const ushort* __restrict__ Wg0, const ushort* __restrict__ Wg1, const ushort* __restrict__ Wg2,
    const float* __restrict__ biasG, float* __restrict__ cst,
    ushort* __restrict__ ho0, ushort* __restrict__ ho1, ushort* __restrict__ ho2)
{
    __shared__ float4 LdsBuf[1024];           // 16 KB: A tile [0,8K), B tile [8K,16K)
    char* LdsA = (char*)LdsBuf;
    char* LdsB = LdsA + 8192;
    int tid = threadIdx.x;
    int bm = blockIdx.x, bn = blockIdx.y;
    int w = tid >> 6, lane = tid & 63;
    int wr = w >> 1, wc = w & 1;
    int r0 = bm * 128;
    int nbase = bn * 128;
    int srow = tid >> 1, sh = tid & 1;        // stager: row 0..127, 32B half

    const ushort* Ax[3] = {x0_, x1_, x2_};
    const ushort* Ah[3] = {hi0, hi1, hi2};
    const ushort* Bg[3] = {Wg0, Wg1, Wg2};
    const int pa[6] = {0, 2, 1, 0, 1, 0};     // smallest products first
    const int pb[6] = {2, 0, 1, 1, 0, 0};

    f32x4 acc[4][4];
    #pragma unroll
    for (int i = 0; i < 4; ++i)
        #pragma unroll
        for (int j = 0; j < 4; ++j) acc[i][j] = (f32x4){0.f, 0.f, 0.f, 0.f};

    for (int p = 0; p < 6; ++p) {
        const ushort* Axp = Ax[pa[p]];
        const ushort* Ahp = Ah[pa[p]];
        const ushort* Bb  = Bg[pb[p]] + (size_t)nbase * 1024;
        for (int kb = 0; kb < 32; ++kb) {
            const ushort* Abase = (kb < 16) ? Axp : Ahp;
            int kloc = (kb & 15) * 32;
            const ushort* as = Abase + (size_t)(r0 + srow) * 512 + kloc + sh * 16;
            uint4 a0 = *(const uint4*)as;
            uint4 a1 = *(const uint4*)(as + 8);
            const ushort* bs = Bb + (size_t)srow * 1024 + kb * 32 + sh * 16;
            uint4 b0 = *(const uint4*)bs;
            uint4 b1 = *(const uint4*)(bs + 8);
            __syncthreads();                  // prev iteration's frag reads done
            *(uint4*)(LdsA + srow * 64 + sh * 32)      = a0;
            *(uint4*)(LdsA + srow * 64 + sh * 32 + 16) = a1;
            *(uint4*)(LdsB + srow * 64 + sh * 32)      = b0;
            *(uint4*)(LdsB + srow * 64 + sh * 32 + 16) = b1;
            __syncthreads();
            short8v af[4], bf[4];
            #pragma unroll
            for (int fm = 0; fm < 4; ++fm)
                af[fm] = *(const short8v*)(LdsA + (wr * 64 + fm * 16 + (lane & 15)) * 64 + (lane >> 4) * 16);
            #pragma unroll
            for (int fn = 0; fn < 4; ++fn)
                bf[fn] = *(const short8v*)(LdsB + (wc * 64 + fn * 16 + (lane & 15)) * 64 + (lane >> 4) * 16);
            #pragma unroll
            for (int fm = 0; fm < 4; ++fm)
                #pragma unroll
                for (int fn = 0; fn < 4; ++fn)
                    acc[fm][fn] = __builtin_amdgcn_mfma_f32_16x16x32_bf16(
                        af[fm], bf[fn], acc[fm][fn], 0, 0, 0);
        }
    }

    // LSTM epilogue (R9-proven): frag fn == gate; unit u fixed per lane.
    int u = (bn * 2 + wc) * 16 + (lane & 15);
    float bI = biasG[u], bF = biasG[512 + u], bG = biasG[1024 + u], bO = biasG[1536 + u];
    #pragma unroll
    for (int fm = 0; fm < 4; ++fm) {
        #pragma unroll
        for (int reg = 0; reg < 4; ++reg) {
            int row = r0 + wr * 64 + fm * 16 + (lane >> 4) * 4 + reg;
            float gi = acc[fm][0][reg] + bI;
            float gf = acc[fm][1][reg] + bF;
            float gg = acc[fm][2][reg] + bG;
            float go = acc[fm][3][reg] + bO;
            size_t ci = (size_t)row * 512 + u;
            float c = cst[ci];
            c = sigmoidf_(gf) * c + sigmoidf_(gi) * tanhf(gg);
            float h = sigmoidf_(go) * tanhf(c);
            cst[ci] = c;
            ushort s0, s1, s2; split3(h, &s0, &s1, &s2);
            ho0[ci] = s0; ho1[ci] = s1; ho2[ci] = s2;
        }
    }
}

// ---- q MFMA for BOTH pending steps (R9 q_mfma + blockIdx.z slot; inner loop verbatim) ----
// slot 0: q_{t-1} from hA (hs[0]); slot 1: q_t from hB (hs[1]). Launched at odd t.
__global__ __launch_bounds__(256) void q2_mfma(
    const ushort* __restrict__ hA0, const ushort* __restrict__ hA1, const ushort* __restrict__ hA2,
    const ushort* __restrict__ hB0, const ushort* __restrict__ hB1, const ushort* __restrict__ hB2,
    const ushort* __restrict__ Wq0, const ushort* __restrict__ Wq1, const ushort* __restrict__ Wq2,
    const float* __restrict__ bq, float* __restrict__ Q2)
{
    __shared__ float4 LdsBuf[1024];
    char* LdsA = (char*)LdsBuf;
    char* LdsB = LdsA + 8192;
    int tid = threadIdx.x;
    int bm = blockIdx.x, bn = blockIdx.y, slot = blockIdx.z;
    int w = tid >> 6, lane = tid & 63;
    int wr = w >> 1, wc = w & 1;
    int r0 = bm * 128;
    int nbase = bn * 128;
    int srow = tid >> 1, sh = tid & 1;

    const ushort* Ah[3];
    if (slot == 0) { Ah[0] = hA0; Ah[1] = hA1; Ah[2] = hA2; }
    else           { Ah[0] = hB0; Ah[1] = hB1; Ah[2] = hB2; }
    float* Qout = Q2 + (size_t)slot * RTOT * 512;
    const ushort* Bg[3] = {Wq0, Wq1, Wq2};
    const int pa[6] = {0, 2, 1, 0, 1, 0};
    const int pb[6] = {2, 0, 1, 1, 0, 0};

    f32x4 acc[4][4];
    #pragma unroll
    for (int i = 0; i < 4; ++i)
        #pragma unroll
        for (int j = 0; j < 4; ++j) acc[i][j] = (f32x4){0.f, 0.f, 0.f, 0.f};

    for (int p = 0; p < 6; ++p) {
        const ushort* Ap = Ah[pa[p]];
        const ushort* Bb = Bg[pb[p]] + (size_t)nbase * 512;
        for (int kb = 0; kb < 16; ++kb) {
            const ushort* as = Ap + (size_t)(r0 + srow) * 512 + kb * 32 + sh * 16;
            uint4 a0 = *(const uint4*)as;
            uint4 a1 = *(const uint4*)(as + 8);
            const ushort* bs = Bb + (size_t)srow * 512 + kb * 32 + sh * 16;
            uint4 b0 = *(const uint4*)bs;
            uint4 b1 = *(const uint4*)(bs + 8);
            __syncthreads();
            *(uint4*)(LdsA + srow * 64 + sh * 32)      = a0;
            *(uint4*)(LdsA + srow * 64 + sh * 32 + 16) = a1;
            *(uint4*)(LdsB + srow * 64 + sh * 32)      = b0;
            *(uint4*)(LdsB + srow * 64 + sh * 32 + 16) = b1;
            __syncthreads();
            short8v af[4], bf[4];
            #pragma unroll
            for (int fm = 0; fm < 4; ++fm)
                af[fm] = *(const short8v*)(LdsA + (wr * 64 + fm * 16 + (lane & 15)) * 64 + (lane >> 4) * 16);
            #pragma unroll
            for (int fn = 0; fn < 4; ++fn)
                bf[fn] = *(const short8v*)(LdsB + (wc * 64 + fn * 16 + (lane & 15)) * 64 + (lane >> 4) * 16);
            #pragma unroll
            for (int fm = 0; fm < 4; ++fm)
                #pragma unroll
                for (int fn = 0; fn < 4; ++fn)
                    acc[fm][fn] = __builtin_amdgcn_mfma_f32_16x16x32_bf16(
                        af[fm], bf[fn], acc[fm][fn], 0, 0, 0);
        }
    }

    #pragma unroll
    for (int fn = 0; fn < 4; ++fn) {
        int col = nbase + wc * 64 + fn * 16 + (lane & 15);
        float bqv = bq[col];
        #pragma unroll
        for (int fm = 0; fm < 4; ++fm)
            #pragma unroll
            for (int reg = 0; reg < 4; ++reg) {
                int row = r0 + wr * 64 + fm * 16 + (lane >> 4) * 4 + reg;
                Qout[(size_t)row * 512 + col] = acc[fm][fn][reg] + bqv;
            }
    }
}

// ---- ctx = enc @ Wc^T, f32 (R1-proven kernel, verbatim) ----
#define BM 128
#define BN 128
#define BKK 16
__global__ __launch_bounds__(256) void gemm_ctx(
    const float* __restrict__ A0, const float* __restrict__ A1, const float* __restrict__ A2,
    const float* __restrict__ B, float* __restrict__ C)
{
    __shared__ float As[BKK][BM + 4];
    __shared__ float Bs[BKK][BN + 4];
    int bm = blockIdx.x, bn = blockIdx.y;
    int tid = threadIdx.x;
    int tm = tid >> 4, tn = tid & 15;
    int lrow = tid >> 2, lc4 = tid & 3;

    int R0 = bm * BM;
    int tau = R0 / (BROWS * PLY);
    const float* enc = (tau == 0) ? A0 : (tau == 1) ? A1 : A2;
    int R = R0 + lrow;
    int rr = R % (BROWS * PLY); int r = rr >> 5; int p = rr & 31;
    const float* a_src0 = enc + (((size_t)((r % KW) * BSZn + r / KW)) * PLY + p) * 512;
    R = R0 + lrow + 64;
    rr = R % (BROWS * PLY); r = rr >> 5; p = rr & 31;
    const float* a_src1 = enc + (((size_t)((r % KW) * BSZn + r / KW)) * PLY + p) * 512;
    const float* b_src0 = B + (size_t)(bn * BN + lrow) * 512;
    const float* b_src1 = b_src0 + (size_t)64 * 512;

    float acc[8][8];
    #pragma unroll
    for (int i = 0; i < 8; ++i)
        #pragma unroll
        for (int j = 0; j < 8; ++j) acc[i][j] = 0.0f;

    float4 a0 = *(const float4*)(a_src0 + lc4 * 4);
    float4 a1 = *(const float4*)(a_src1 + lc4 * 4);
    float4 b0 = *(const float4*)(b_src0 + lc4 * 4);
    float4 b1 = *(const float4*)(b_src1 + lc4 * 4);

    for (int t = 0; t < 512 / BKK; ++t) {
        __syncthreads();
        As[lc4 * 4 + 0][lrow] = a0.x; As[lc4 * 4 + 1][lrow] = a0.y;
        As[lc4 * 4 + 2][lrow] = a0.z; As[lc4 * 4 + 3][lrow] = a0.w;
        As[lc4 * 4 + 0][lrow + 64] = a1.x; As[lc4 * 4 + 1][lrow + 64] = a1.y;
        As[lc4 * 4 + 2][lrow + 64] = a1.z; As[lc4 * 4 + 3][lrow + 64] = a1.w;
        Bs[lc4 * 4 + 0][lrow] = b0.x; Bs[lc4 * 4 + 1][lrow] = b0.y;
        Bs[lc4 * 4 + 2][lrow] = b0.z; Bs[lc4 * 4 + 3][lrow] = b0.w;
        Bs[lc4 * 4 + 0][lrow + 64] = b1.x; Bs[lc4 * 4 + 1][lrow + 64] = b1.y;
        Bs[lc4 * 4 + 2][lrow + 64] = b1.z; Bs[lc4 * 4 + 3][lrow + 64] = b1.w;
        __syncthreads();
        if (t + 1 < 512 / BKK) {
            int k0 = (t + 1) * BKK + lc4 * 4;
            a0 = *(const float4*)(a_src0 + k0);
            a1 = *(const float4*)(a_src1 + k0);
            b0 = *(const float4*)(b_src0 + k0);
            b1 = *(const float4*)(b_src1 + k0);
        }
        #pragma unroll
        for (int k = 0; k < BKK; ++k) {
            float af[8], bf[8];
            *(float4*)&af[0] = *(const float4*)&As[k][tm * 8];
            *(float4*)&af[4] = *(const float4*)&As[k][tm * 8 + 4];
            *(float4*)&bf[0] = *(const float4*)&Bs[k][tn * 8];
            *(float4*)&bf[4] = *(const float4*)&Bs[k][tn * 8 + 4];
            #pragma unroll
            for (int i = 0; i < 8; ++i)
                #pragma unroll
                for (int j = 0; j < 8; ++j)
                    acc[i][j] = fmaf(af[i], bf[j], acc[i][j]);
        }
    }
    int row0 = bm * BM + tm * 8;
    int col0 = bn * BN + tn * 8;
    #pragma unroll
    for (int i = 0; i < 8; ++i) {
        float* cr = C + (size_t)(row0 + i) * 512 + col0;
        float4 o0, o1;
        o0.x = acc[i][0]; o0.y = acc[i][1]; o0.z = acc[i][2]; o0.w = acc[i][3];
        o1.x = acc[i][4]; o1.y = acc[i][5]; o1.z = acc[i][6]; o1.w = acc[i][7];
        *(float4*)cr = o0;
        *(float4*)(cr + 4) = o1;
    }
}

// ---- attention, 2 steps per ctx load (R10/R11-proven, verbatim) ----
__global__ __launch_bounds__(256) void attn2r(
    const float* __restrict__ Q2, const float* __restrict__ ctx,
    const float* __restrict__ vvec, float* __restrict__ out, int tbase)
{
    int row = blockIdx.x, tid = threadIdx.x;
    int w = tid >> 6, lane = tid & 63;
    __shared__ float scs[2][PLY];

    const float* q0 = Q2 + (size_t)row * 512 + lane * 8;                 // slot 0 (even step)
    const float* q1 = Q2 + ((size_t)RTOT + row) * 512 + lane * 8;        // slot 1
    const float* ctxr = ctx + (size_t)row * PLY * 512 + lane * 8;
    float qa[8], qb[8], vv[8];
    *(float4*)&qa[0] = *(const float4*)(q0);
    *(float4*)&qa[4] = *(const float4*)(q0 + 4);
    *(float4*)&qb[0] = *(const float4*)(q1);
    *(float4*)&qb[4] = *(const float4*)(q1 + 4);
    *(float4*)&vv[0] = *(const float4*)(vvec + lane * 8);
    *(float4*)&vv[4] = *(const float4*)(vvec + lane * 8 + 4);

    for (int pp = 0; pp < 8; ++pp) {
        int p = w * 8 + pp;
        const float* cp = ctxr + (size_t)p * 512;
        float cv[8];
        *(float4*)&cv[0] = *(const float4*)(cp);
        *(float4*)&cv[4] = *(const float4*)(cp + 4);
        float a0 = 0.0f, a1 = 0.0f;
        #pragma unroll
        for (int j = 0; j < 8; ++j) {
            a0 += tanhf(qa[j] + cv[j]) * vv[j];
            a1 += tanhf(qb[j] + cv[j]) * vv[j];
        }
        #pragma unroll
        for (int off = 1; off < 64; off <<= 1) {
            a0 += __shfl_xor(a0, off);
            a1 += __shfl_xor(a1, off);
        }
        if (lane == 0) { scs[0][p] = a0; scs[1][p] = a1; }
    }
    __syncthreads();

    if (tid < 64) {
        int w2 = tid >> 5, l = tid & 31;
        float x = scs[w2][l];
        float bvv = x; int bi = l;
        #pragma unroll
        for (int off = 1; off < 32; off <<= 1) {
            float ov = __shfl_xor(bvv, off, 32);
            int oi = __shfl_xor(bi, off, 32);
            if (ov > bvv || (ov == bvv && oi < bi)) { bvv = ov; bi = oi; }
        }
        float s = expf(x - bvv);
        #pragma unroll
        for (int off = 1; off < 32; off <<= 1) s += __shfl_xor(s, off, 32);
        float lse = logf(s);
        int t = tbase + w2;
        int tau = row / BROWS, r = row % BROWS;
        out[(size_t)tau * (BROWS * 1024) + (size_t)r * 1024 + t * 32 + l] = x - bvv - lse;
        if (l == 0)
            out[(size_t)3 * (BROWS * 1024) + (size_t)tau * (BROWS * 32) + r * 32 + t] = (float)bi;
    }
}

extern "C" void kernel_launch(void* const* d_in, const int* in_sizes, int n_in,
                              void* d_out, int out_size, void* d_ws, size_t ws_size,
                              hipStream_t stream)
{
    const float* home = (const float*)d_in[0];
    const int*   hidx = (const int*)d_in[1];
    const float* vis  = (const float*)d_in[2];
    const int*   vidx = (const int*)d_in[3];
    const float* team = (const float*)d_in[4];
    const int*   tidx = (const int*)d_in[5];
    const float* init_embed = (const float*)d_in[6];
    const float* W_ih = (const float*)d_in[7];
    const float* W_hh = (const float*)d_in[8];
    const float* b_ih = (const float*)d_in[9];
    const float* b_hh = (const float*)d_in[10];
    const float* Wq   = (const float*)d_in[11];
    const float* bq   = (const float*)d_in[12];
    const float* Wc   = (const float*)d_in[13];
    const float* vvec = (const float*)d_in[14];
    float* out = (float*)d_out;
    (void)in_sizes; (void)n_in; (void)out_size; (void)ws_size;

    char* wsb = (char*)d_ws;
    float* ctx   = (float*)wsb; wsb += (size_t)RTOT * PLY * 512 * 4;   // 302.0 MB
    float* cst   = (float*)wsb; wsb += (size_t)RTOT * 512 * 4;         // 9.4 MB
    float* Q2    = (float*)wsb; wsb += (size_t)2 * RTOT * 512 * 4;     // 18.9 MB
    float* biasG = (float*)wsb; wsb += 2048 * 4;
    ushort* Wg[3], *Wq3[3], *xs[3], *hs[2][3];
    for (int i = 0; i < 3; ++i) { Wg[i]  = (ushort*)wsb; wsb += (size_t)2048 * 1024 * 2; }
    for (int i = 0; i < 3; ++i) { Wq3[i] = (ushort*)wsb; wsb += (size_t)512 * 512 * 2; }
    for (int i = 0; i < 3; ++i) { xs[i]  = (ushort*)wsb; wsb += (size_t)RTOT * 512 * 2; }
    for (int b = 0; b < 2; ++b)
        for (int i = 0; i < 3; ++i) { hs[b][i] = (ushort*)wsb; wsb += (size_t)RTOT * 512 * 2; }
    // total ~386.9 MB (proven fit in R9)

    prep_split<<<2560, 256, 0, stream>>>(W_ih, W_hh, Wq, b_ih, b_hh,
                                         Wg[0], Wg[1], Wg[2], Wq3[0], Wq3[1], Wq3[2], biasG);
    initsplit<<<RTOT, 256, 0, stream>>>(home, vis, team, init_embed, cst,
                                        hs[1][0], hs[1][1], hs[1][2],
                                        xs[0], xs[1], xs[2]);
    gemm_ctx<<<dim3(RTOT * PLY / BM, 512 / BN), 256, 0, stream>>>(home, vis, team, Wc, ctx);

    for (int t = 0; t < 32; ++t) {
        int hin = (t + 1) & 1, hout = t & 1;
        gates_mfma<<<dim3(36, 16), 256, 0, stream>>>(
            xs[0], xs[1], xs[2],
            hs[hin][0], hs[hin][1], hs[hin][2],
            Wg[0], Wg[1], Wg[2], biasG, cst,
            hs[hout][0], hs[hout][1], hs[hout][2]);
        if (t < 31)
            xprep<<<RTOT, 256, 0, stream>>>(home, vis, team, hidx, vidx, tidx,
                                            xs[0], xs[1], xs[2], t);
        if (t & 1) {
            // h_{t-1} in hs[0], h_t in hs[1]: compute q_{t-1} (slot 0) + q_t (slot 1)
            q2_mfma<<<dim3(36, 4, 2), 256, 0, stream>>>(
                hs[0][0], hs[0][1], hs[0][2],
                hs[1][0], hs[1][1], hs[1][2],
                Wq3[0], Wq3[1], Wq3[2], bq, Q2);
            attn2r<<<RTOT, 256, 0, stream>>>(Q2, ctx, vvec, out, t - 1);
        }
    }
}

// Round 13
// 9668.665 us; speedup vs baseline: 2.0104x; 1.1043x over previous
//
#include <hip/hip_runtime.h>
#include <hip/hip_bf16.h>
#include <math.h>

#define KW 24
#define BSZn 64
#define PLY 32
#define BROWS 1536            // BSZ*KW rows per task
#define RTOT 4608             // 3*BROWS

typedef __attribute__((ext_vector_type(8))) short short8v;  // 8 bf16 (4 VGPRs)
typedef __attribute__((ext_vector_type(4))) float f32x4;

__device__ __forceinline__ float sigmoidf_(float x) { return 1.0f / (1.0f + expf(-x)); }

// exact 3-way bf16 split: v = s0 + s1 + s2 + O(2^-26 v)
__device__ __forceinline__ void split3(float v, ushort* a, ushort* b, ushort* c)
{
    __hip_bfloat16 h1 = __float2bfloat16(v);  float f1 = __bfloat162float(h1);
    float r1 = v - f1;
    __hip_bfloat16 h2 = __float2bfloat16(r1); float f2 = __bfloat162float(h2);
    float r2 = r1 - f2;
    __hip_bfloat16 h3 = __float2bfloat16(r2);
    *a = *(ushort*)&h1; *b = *(ushort*)&h2; *c = *(ushort*)&h3;
}

// ---- weights prep (R9-proven, verbatim) ----
__global__ void prep_split(const float* __restrict__ W_ih, const float* __restrict__ W_hh,
                           const float* __restrict__ Wq,
                           const float* __restrict__ b_ih, const float* __restrict__ b_hh,
                           ushort* __restrict__ Wg0, ushort* __restrict__ Wg1, ushort* __restrict__ Wg2,
                           ushort* __restrict__ Wq0, ushort* __restrict__ Wq1, ushort* __restrict__ Wq2,
                           float* __restrict__ biasG)
{
    int n = blockIdx.x, tid = threadIdx.x;     // 0..2559
    if (n < 2048) {
        int ublk = n >> 6, gate = (n >> 4) & 3, ui = n & 15;
        int src = gate * 512 + ublk * 16 + ui;
        for (int k = tid; k < 1024; k += 256) {
            float v = (k < 512) ? W_ih[(size_t)src * 512 + k]
                                : W_hh[(size_t)src * 512 + (k - 512)];
            ushort s0, s1, s2; split3(v, &s0, &s1, &s2);
            Wg0[(size_t)n * 1024 + k] = s0;
            Wg1[(size_t)n * 1024 + k] = s1;
            Wg2[(size_t)n * 1024 + k] = s2;
        }
        if (tid == 0) biasG[src] = b_ih[src] + b_hh[src];
    } else {
        int n2 = n - 2048;
        for (int k = tid; k < 512; k += 256) {
            ushort s0, s1, s2; split3(Wq[(size_t)n2 * 512 + k], &s0, &s1, &s2);
            Wq0[(size_t)n2 * 512 + k] = s0;
            Wq1[(size_t)n2 * 512 + k] = s1;
            Wq2[(size_t)n2 * 512 + k] = s2;
        }
    }
}

// ---- init (R9-proven, verbatim) ----
__global__ void initsplit(const float* __restrict__ home, const float* __restrict__ vis,
                          const float* __restrict__ team, const float* __restrict__ init_embed,
                          float* __restrict__ cst,
                          ushort* __restrict__ h0_, ushort* __restrict__ h1_, ushort* __restrict__ h2_,
                          ushort* __restrict__ x0_, ushort* __restrict__ x1_, ushort* __restrict__ x2_)
{
    int row = blockIdx.x, tid = threadIdx.x;
    int tau = row / BROWS, r = row % BROWS;
    const float* enc = (tau == 0) ? home : (tau == 1) ? vis : team;
    const float* base = enc + ((size_t)((r % KW) * BSZn + r / KW) * PLY) * 512;
    for (int e = tid; e < 512; e += 256) {
        float s = 0.0f;
        for (int p = 0; p < PLY; ++p) s += base[(size_t)p * 512 + e];
        size_t o = (size_t)row * 512 + e;
        cst[o] = s;
        ushort a, b, c;
        split3(s, &a, &b, &c);
        h0_[o] = a; h1_[o] = b; h2_[o] = c;
        split3(init_embed[e], &a, &b, &c);
        x0_[o] = a; x1_[o] = b; x2_[o] = c;
    }
}

// ---- gather x_{t+1} and split (R9-proven, verbatim) ----
__global__ void xprep(const float* __restrict__ home, const float* __restrict__ vis,
                      const float* __restrict__ team,
                      const int* __restrict__ hidx, const int* __restrict__ vidx,
                      const int* __restrict__ tidx,
                      ushort* __restrict__ x0_, ushort* __restrict__ x1_, ushort* __restrict__ x2_,
                      int t)
{
    int row = blockIdx.x, tid = threadIdx.x;
    int tau = row / BROWS, r = row % BROWS;
    const float* enc = (tau == 0) ? home : (tau == 1) ? vis : team;
    const int* idx = (tau == 0) ? hidx : (tau == 1) ? vidx : tidx;
    int j = idx[r * PLY + t];
    const float* src = enc + ((size_t)((r % KW) * BSZn + r / KW) * PLY + j) * 512;
    for (int e = tid; e < 512; e += 256) {
        size_t o = (size_t)row * 512 + e;
        ushort a, b, c; split3(src[e], &a, &b, &c);
        x0_[o] = a; x1_[o] = b; x2_[o] = c;
    }
}

// ---- gates MFMA v13: pass-grouped by A-plane ----
// Per K-chunk kb: stage 3 B planes ONCE (persistent regions) + A region 3x
// (once per group). Groups: {A0: B2,B1,B0}, {A1: B1,B0}, {A2: B0} == the same
// 6 products a+b<=2 as R9. A-frags held in registers across each group.
// Stagings/kb 12->6, barriers 12->6, frag reads/wave 48->36, global A/B reads halved.
// LDS 32 KB (A 8K + B0/B1/B2 8K each). Frag addressing identical to R9.
__global__ __launch_bounds__(256) void gates_mfma(
    const ushort* __restrict__ x0_, const ushort* __restrict__ x1_, const ushort* __restrict__ x2_,
    const ushort* __restrict__ hi0, const ushort* __restrict__ hi1, const ushort* __restrict__ hi2,
    const ushort* __restrict__ Wg0, const ushort* __restrict__ Wg1, const ushort* __restrict__ Wg2,
    const float* __restrict__ biasG, float* __restrict__ cst,
    ushort* __restrict__ ho0, ushort* __restrict__ ho1, ushort* __restrict__ ho2)
{
    __shared__ float4 LdsBuf[2048];           // 32 KB: A [0,8K) | B0 | B1 | B2
    char* LdsA = (char*)LdsBuf;
    int tid = threadIdx.x;
    int bm = blockIdx.x, bn = blockIdx.y;
    int w = tid >> 6, lane = tid & 63;
    int wr = w >> 1, wc = w & 1;
    int r0 = bm * 128;
    int nbase = bn * 128;
    int srow = tid >> 1, sh = tid & 1;        // stager: row 0..127, 32B half

    const ushort* Ax[3] = {x0_, x1_, x2_};
    const ushort* Ah[3] = {hi0, hi1, hi2};
    const ushort* Bg[3] = {Wg0, Wg1, Wg2};

    f32x4 acc[4][4];
    #pragma unroll
    for (int i = 0; i < 4; ++i)
        #pragma unroll
        for (int j = 0; j < 4; ++j) acc[i][j] = (f32x4){0.f, 0.f, 0.f, 0.f};

    size_t aoffg = (size_t)(r0 + srow) * 512 + sh * 16;          // global A elem offset
    size_t boffg = (size_t)(nbase + srow) * 1024 + sh * 16;      // global B elem offset
    int lws = srow * 64 + sh * 32;                               // LDS byte offset in region

    for (int kb = 0; kb < 32; ++kb) {
        int kloc = (kb & 15) * 32;
        bool usex = (kb < 16);
        // ---- stage A plane 0 + all 3 B planes for this kb ----
        {
            const ushort* ap = (usex ? Ax[0] : Ah[0]) + aoffg + kloc;
            uint4 a0 = *(const uint4*)ap;
            uint4 a1 = *(const uint4*)(ap + 8);
            uint4 b00, b01, b10, b11, b20, b21;
            {
                const ushort* bp = Bg[0] + boffg + kb * 32;
                b00 = *(const uint4*)bp; b01 = *(const uint4*)(bp + 8);
                bp = Bg[1] + boffg + kb * 32;
                b10 = *(const uint4*)bp; b11 = *(const uint4*)(bp + 8);
                bp = Bg[2] + boffg + kb * 32;
                b20 = *(const uint4*)bp; b21 = *(const uint4*)(bp + 8);
            }
            __syncthreads();                  // prev kb's A/B region reads done
            *(uint4*)(LdsA + lws)              = a0;
            *(uint4*)(LdsA + lws + 16)         = a1;
            *(uint4*)(LdsA + 8192 + lws)       = b00;
            *(uint4*)(LdsA + 8192 + lws + 16)  = b01;
            *(uint4*)(LdsA + 16384 + lws)      = b10;
            *(uint4*)(LdsA + 16384 + lws + 16) = b11;
            *(uint4*)(LdsA + 24576 + lws)      = b20;
            *(uint4*)(LdsA + 24576 + lws + 16) = b21;
            __syncthreads();
        }
        // ---- groups: a = 0 (B2,B1,B0), 1 (B1,B0), 2 (B0) ----
        #pragma unroll
        for (int a = 0; a < 3; ++a) {
            if (a > 0) {
                // restage A region with plane a
                const ushort* ap = (usex ? Ax[a] : Ah[a]) + aoffg + kloc;
                uint4 a0 = *(const uint4*)ap;
                uint4 a1 = *(const uint4*)(ap + 8);
                __syncthreads();              // all waves consumed A-plane (a-1) frags
                *(uint4*)(LdsA + lws)      = a0;
                *(uint4*)(LdsA + lws + 16) = a1;
                __syncthreads();
            }
            short8v af[4];
            #pragma unroll
            for (int fm = 0; fm < 4; ++fm)
                af[fm] = *(const short8v*)(LdsA + (wr * 64 + fm * 16 + (lane & 15)) * 64 + (lane >> 4) * 16);
            #pragma unroll
            for (int b = 2; b >= 0; --b) {    // smallest products first within group
                if (a + b > 2) continue;
                const char* LdsB = LdsA + 8192 + b * 8192;
                short8v bf[4];
                #pragma unroll
                for (int fn = 0; fn < 4; ++fn)
                    bf[fn] = *(const short8v*)(LdsB + (wc * 64 + fn * 16 + (lane & 15)) * 64 + (lane >> 4) * 16);
                #pragma unroll
                for (int fm = 0; fm < 4; ++fm)
                    #pragma unroll
                    for (int fn = 0; fn < 4; ++fn)
                        acc[fm][fn] = __builtin_amdgcn_mfma_f32_16x16x32_bf16(
                            af[fm], bf[fn], acc[fm][fn], 0, 0, 0);
            }
        }
    }

    // LSTM epilogue (R9-proven): frag fn == gate; unit u fixed per lane.
    int u = (bn * 2 + wc) * 16 + (lane & 15);
    float bI = biasG[u], bF = biasG[512 + u], bG = biasG[1024 + u], bO = biasG[1536 + u];
    #pragma unroll
    for (int fm = 0; fm < 4; ++fm) {
        #pragma unroll
        for (int reg = 0; reg < 4; ++reg) {
            int row = r0 + wr * 64 + fm * 16 + (lane >> 4) * 4 + reg;
            float gi = acc[fm][0][reg] + bI;
            float gf = acc[fm][1][reg] + bF;
            float gg = acc[fm][2][reg] + bG;
            float go = acc[fm][3][reg] + bO;
            size_t ci = (size_t)row * 512 + u;
            float c = cst[ci];
            c = sigmoidf_(gf) * c + sigmoidf_(gi) * tanhf(gg);
            float h = sigmoidf_(go) * tanhf(c);
            cst[ci] = c;
            ushort s0, s1, s2; split3(h, &s0, &s1, &s2);
            ho0[ci] = s0; ho1[ci] = s1; ho2[ci] = s2;
        }
    }
}

// ---- q MFMA for BOTH pending steps (R12-proven, verbatim) ----
__global__ __launch_bounds__(256) void q2_mfma(
    const ushort* __restrict__ hA0, const ushort* __restrict__ hA1, const ushort* __restrict__ hA2,
    const ushort* __restrict__ hB0, const ushort* __restrict__ hB1, const ushort* __restrict__ hB2,
    const ushort* __restrict__ Wq0, const ushort* __restrict__ Wq1, const ushort* __restrict__ Wq2,
    const float* __restrict__ bq, float* __restrict__ Q2)
{
    __shared__ float4 LdsBuf[1024];
    char* LdsA = (char*)LdsBuf;
    char* LdsB = LdsA + 8192;
    int tid = threadIdx.x;
    int bm = blockIdx.x, bn = blockIdx.y, slot = blockIdx.z;
    int w = tid >> 6, lane = tid & 63;
    int wr = w >> 1, wc = w & 1;
    int r0 = bm * 128;
    int nbase = bn * 128;
    int srow = tid >> 1, sh = tid & 1;

    const ushort* Ah[3];
    if (slot == 0) { Ah[0] = hA0; Ah[1] = hA1; Ah[2] = hA2; }
    else           { Ah[0] = hB0; Ah[1] = hB1; Ah[2] = hB2; }
    float* Qout = Q2 + (size_t)slot * RTOT * 512;
    const ushort* Bg[3] = {Wq0, Wq1, Wq2};
    const int pa[6] = {0, 2, 1, 0, 1, 0};
    const int pb[6] = {2, 0, 1, 1, 0, 0};

    f32x4 acc[4][4];
    #pragma unroll
    for (int i = 0; i < 4; ++i)
        #pragma unroll
        for (int j = 0; j < 4; ++j) acc[i][j] = (f32x4){0.f, 0.f, 0.f, 0.f};

    for (int p = 0; p < 6; ++p) {
        const ushort* Ap = Ah[pa[p]];
        const ushort* Bb = Bg[pb[p]] + (size_t)nbase * 512;
        for (int kb = 0; kb < 16; ++kb) {
            const ushort* as = Ap + (size_t)(r0 + srow) * 512 + kb * 32 + sh * 16;
            uint4 a0 = *(const uint4*)as;
            uint4 a1 = *(const uint4*)(as + 8);
            const ushort* bs = Bb + (size_t)srow * 512 + kb * 32 + sh * 16;
            uint4 b0 = *(const uint4*)bs;
            uint4 b1 = *(const uint4*)(bs + 8);
            __syncthreads();
            *(uint4*)(LdsA + srow * 64 + sh * 32)      = a0;
            *(uint4*)(LdsA + srow * 64 + sh * 32 + 16) = a1;
            *(uint4*)(LdsB + srow * 64 + sh * 32)      = b0;
            *(uint4*)(LdsB + srow * 64 + sh * 32 + 16) = b1;
            __syncthreads();
            short8v af[4], bf[4];
            #pragma unroll
            for (int fm = 0; fm < 4; ++fm)
                af[fm] = *(const short8v*)(LdsA + (wr * 64 + fm * 16 + (lane & 15)) * 64 + (lane >> 4) * 16);
            #pragma unroll
            for (int fn = 0; fn < 4; ++fn)
                bf[fn] = *(const short8v*)(LdsB + (wc * 64 + fn * 16 + (lane & 15)) * 64 + (lane >> 4) * 16);
            #pragma unroll
            for (int fm = 0; fm < 4; ++fm)
                #pragma unroll
                for (int fn = 0; fn < 4; ++fn)
                    acc[fm][fn] = __builtin_amdgcn_mfma_f32_16x16x32_bf16(
                        af[fm], bf[fn], acc[fm][fn], 0, 0, 0);
        }
    }

    #pragma unroll
    for (int fn = 0; fn < 4; ++fn) {
        int col = nbase + wc * 64 + fn * 16 + (lane & 15);
        float bqv = bq[col];
        #pragma unroll
        for (int fm = 0; fm < 4; ++fm)
            #pragma unroll
            for (int reg = 0; reg < 4; ++reg) {
                int row = r0 + wr * 64 + fm * 16 + (lane >> 4) * 4 + reg;
                Qout[(size_t)row * 512 + col] = acc[fm][fn][reg] + bqv;
            }
    }
}

// ---- ctx = enc @ Wc^T, f32 (R1-proven kernel, verbatim) ----
#define BM 128
#define BN 128
#define BKK 16
__global__ __launch_bounds__(256) void gemm_ctx(
    const float* __restrict__ A0, const float* __restrict__ A1, const float* __restrict__ A2,
    const float* __restrict__ B, float* __restrict__ C)
{
    __shared__ float As[BKK][BM + 4];
    __shared__ float Bs[BKK][BN + 4];
    int bm = blockIdx.x, bn = blockIdx.y;
    int tid = threadIdx.x;
    int tm = tid >> 4, tn = tid & 15;
    int lrow = tid >> 2, lc4 = tid & 3;

    int R0 = bm * BM;
    int tau = R0 / (BROWS * PLY);
    const float* enc = (tau == 0) ? A0 : (tau == 1) ? A1 : A2;
    int R = R0 + lrow;
    int rr = R % (BROWS * PLY); int r = rr >> 5; int p = rr & 31;
    const float* a_src0 = enc + (((size_t)((r % KW) * BSZn + r / KW)) * PLY + p) * 512;
    R = R0 + lrow + 64;
    rr = R % (BROWS * PLY); r = rr >> 5; p = rr & 31;
    const float* a_src1 = enc + (((size_t)((r % KW) * BSZn + r / KW)) * PLY + p) * 512;
    const float* b_src0 = B + (size_t)(bn * BN + lrow) * 512;
    const float* b_src1 = b_src0 + (size_t)64 * 512;

    float acc[8][8];
    #pragma unroll
    for (int i = 0; i < 8; ++i)
        #pragma unroll
        for (int j = 0; j < 8; ++j) acc[i][j] = 0.0f;

    float4 a0 = *(const float4*)(a_src0 + lc4 * 4);
    float4 a1 = *(const float4*)(a_src1 + lc4 * 4);
    float4 b0 = *(const float4*)(b_src0 + lc4 * 4);
    float4 b1 = *(const float4*)(b_src1 + lc4 * 4);

    for (int t = 0; t < 512 / BKK; ++t) {
        __syncthreads();
        As[lc4 * 4 + 0][lrow] = a0.x; As[lc4 * 4 + 1][lrow] = a0.y;
        As[lc4 * 4 + 2][lrow] = a0.z; As[lc4 * 4 + 3][lrow] = a0.w;
        As[lc4 * 4 + 0][lrow + 64] = a1.x; As[lc4 * 4 + 1][lrow + 64] = a1.y;
        As[lc4 * 4 + 2][lrow + 64] = a1.z; As[lc4 * 4 + 3][lrow + 64] = a1.w;
        Bs[lc4 * 4 + 0][lrow] = b0.x; Bs[lc4 * 4 + 1][lrow] = b0.y;
        Bs[lc4 * 4 + 2][lrow] = b0.z; Bs[lc4 * 4 + 3][lrow] = b0.w;
        Bs[lc4 * 4 + 0][lrow + 64] = b1.x; Bs[lc4 * 4 + 1][lrow + 64] = b1.y;
        Bs[lc4 * 4 + 2][lrow + 64] = b1.z; Bs[lc4 * 4 + 3][lrow + 64] = b1.w;
        __syncthreads();
        if (t + 1 < 512 / BKK) {
            int k0 = (t + 1) * BKK + lc4 * 4;
            a0 = *(const float4*)(a_src0 + k0);
            a1 = *(const float4*)(a_src1 + k0);
            b0 = *(const float4*)(b_src0 + k0);
            b1 = *(const float4*)(b_src1 + k0);
        }
        #pragma unroll
        for (int k = 0; k < BKK; ++k) {
            float af[8], bf[8];
            *(float4*)&af[0] = *(const float4*)&As[k][tm * 8];
            *(float4*)&af[4] = *(const float4*)&As[k][tm * 8 + 4];
            *(float4*)&bf[0] = *(const float4*)&Bs[k][tn * 8];
            *(float4*)&bf[4] = *(const float4*)&Bs[k][tn * 8 + 4];
            #pragma unroll
            for (int i = 0; i < 8; ++i)
                #pragma unroll
                for (int j = 0; j < 8; ++j)
                    acc[i][j] = fmaf(af[i], bf[j], acc[i][j]);
        }
    }
    int row0 = bm * BM + tm * 8;
    int col0 = bn * BN + tn * 8;
    #pragma unroll
    for (int i = 0; i < 8; ++i) {
        float* cr = C + (size_t)(row0 + i) * 512 + col0;
        float4 o0, o1;
        o0.x = acc[i][0]; o0.y = acc[i][1]; o0.z = acc[i][2]; o0.w = acc[i][3];
        o1.x = acc[i][4]; o1.y = acc[i][5]; o1.z = acc[i][6]; o1.w = acc[i][7];
        *(float4*)cr = o0;
        *(float4*)(cr + 4) = o1;
    }
}

// ---- attention, 2 steps per ctx load (R10/R12-proven, verbatim) ----
__global__ __launch_bounds__(256) void attn2r(
    const float* __restrict__ Q2, const float* __restrict__ ctx,
    const float* __restrict__ vvec, float* __restrict__ out, int tbase)
{
    int row = blockIdx.x, tid = threadIdx.x;
    int w = tid >> 6, lane = tid & 63;
    __shared__ float scs[2][PLY];

    const float* q0 = Q2 + (size_t)row * 512 + lane * 8;                 // slot 0 (even step)
    const float* q1 = Q2 + ((size_t)RTOT + row) * 512 + lane * 8;        // slot 1
    const float* ctxr = ctx + (size_t)row * PLY * 512 + lane * 8;
    float qa[8], qb[8], vv[8];
    *(float4*)&qa[0] = *(const float4*)(q0);
    *(float4*)&qa[4] = *(const float4*)(q0 + 4);
    *(float4*)&qb[0] = *(const float4*)(q1);
    *(float4*)&qb[4] = *(const float4*)(q1 + 4);
    *(float4*)&vv[0] = *(const float4*)(vvec + lane * 8);
    *(float4*)&vv[4] = *(const float4*)(vvec + lane * 8 + 4);

    for (int pp = 0; pp < 8; ++pp) {
        int p = w * 8 + pp;
        const float* cp = ctxr + (size_t)p * 512;
        float cv[8];
        *(float4*)&cv[0] = *(const float4*)(cp);
        *(float4*)&cv[4] = *(const float4*)(cp + 4);
        float a0 = 0.0f, a1 = 0.0f;
        #pragma unroll
        for (int j = 0; j < 8; ++j) {
            a0 += tanhf(qa[j] + cv[j]) * vv[j];
            a1 += tanhf(qb[j] + cv[j]) * vv[j];
        }
        #pragma unroll
        for (int off = 1; off < 64; off <<= 1) {
            a0 += __shfl_xor(a0, off);
            a1 += __shfl_xor(a1, off);
        }
        if (lane == 0) { scs[0][p] = a0; scs[1][p] = a1; }
    }
    __syncthreads();

    if (tid < 64) {
        int w2 = tid >> 5, l = tid & 31;
        float x = scs[w2][l];
        float bvv = x; int bi = l;
        #pragma unroll
        for (int off = 1; off < 32; off <<= 1) {
            float ov = __shfl_xor(bvv, off, 32);
            int oi = __shfl_xor(bi, off, 32);
            if (ov > bvv || (ov == bvv && oi < bi)) { bvv = ov; bi = oi; }
        }
        float s = expf(x - bvv);
        #pragma unroll
        for (int off = 1; off < 32; off <<= 1) s += __shfl_xor(s, off, 32);
        float lse = logf(s);
        int t = tbase + w2;
        int tau = row / BROWS, r = row % BROWS;
        out[(size_t)tau * (BROWS * 1024) + (size_t)r * 1024 + t * 32 + l] = x - bvv - lse;
        if (l == 0)
            out[(size_t)3 * (BROWS * 1024) + (size_t)tau * (BROWS * 32) + r * 32 + t] = (float)bi;
    }
}

extern "C" void kernel_launch(void* const* d_in, const int* in_sizes, int n_in,
                              void* d_out, int out_size, void* d_ws, size_t ws_size,
                              hipStream_t stream)
{
    const float* home = (const float*)d_in[0];
    const int*   hidx = (const int*)d_in[1];
    const float* vis  = (const float*)d_in[2];
    const int*   vidx = (const int*)d_in[3];
    const float* team = (const float*)d_in[4];
    const int*   tidx = (const int*)d_in[5];
    const float* init_embed = (const float*)d_in[6];
    const float* W_ih = (const float*)d_in[7];
    const float* W_hh = (const float*)d_in[8];
    const float* b_ih = (const float*)d_in[9];
    const float* b_hh = (const float*)d_in[10];
    const float* Wq   = (const float*)d_in[11];
    const float* bq   = (const float*)d_in[12];
    const float* Wc   = (const float*)d_in[13];
    const float* vvec = (const float*)d_in[14];
    float* out = (float*)d_out;
    (void)in_sizes; (void)n_in; (void)out_size; (void)ws_size;

    char* wsb = (char*)d_ws;
    float* ctx   = (float*)wsb; wsb += (size_t)RTOT * PLY * 512 * 4;   // 302.0 MB
    float* cst   = (float*)wsb; wsb += (size_t)RTOT * 512 * 4;         // 9.4 MB
    float* Q2    = (float*)wsb; wsb += (size_t)2 * RTOT * 512 * 4;     // 18.9 MB
    float* biasG = (float*)wsb; wsb += 2048 * 4;
    ushort* Wg[3], *Wq3[3], *xs[3], *hs[2][3];
    for (int i = 0; i < 3; ++i) { Wg[i]  = (ushort*)wsb; wsb += (size_t)2048 * 1024 * 2; }
    for (int i = 0; i < 3; ++i) { Wq3[i] = (ushort*)wsb; wsb += (size_t)512 * 512 * 2; }
    for (int i = 0; i < 3; ++i) { xs[i]  = (ushort*)wsb; wsb += (size_t)RTOT * 512 * 2; }
    for (int b = 0; b < 2; ++b)
        for (int i = 0; i < 3; ++i) { hs[b][i] = (ushort*)wsb; wsb += (size_t)RTOT * 512 * 2; }
    // total ~386.9 MB (proven fit in R9)

    prep_split<<<2560, 256, 0, stream>>>(W_ih, W_hh, Wq, b_ih, b_hh,
                                         Wg[0], Wg[1], Wg[2], Wq3[0], Wq3[1], Wq3[2], biasG);
    initsplit<<<RTOT, 256, 0, stream>>>(home, vis, team, init_embed, cst,
                                        hs[1][0], hs[1][1], hs[1][2],
                                        xs[0], xs[1], xs[2]);
    gemm_ctx<<<dim3(RTOT * PLY / BM, 512 / BN), 256, 0, stream>>>(home, vis, team, Wc, ctx);

    for (int t = 0; t < 32; ++t) {
        int hin = (t + 1) & 1, hout = t & 1;
        gates_mfma<<<dim3(36, 16), 256, 0, stream>>>(
            xs[0], xs[1], xs[2],
            hs[hin][0], hs[hin][1], hs[hin][2],
            Wg[0], Wg[1], Wg[2], biasG, cst,
            hs[hout][0], hs[hout][1], hs[hout][2]);
        if (t < 31)
            xprep<<<RTOT, 256, 0, stream>>>(home, vis, team, hidx, vidx, tidx,
                                            xs[0], xs[1], xs[2], t);
        if (t & 1) {
            // h_{t-1} in hs[0], h_t in hs[1]: compute q_{t-1} (slot 0) + q_t (slot 1)
            q2_mfma<<<dim3(36, 4, 2), 256, 0, stream>>>(
                hs[0][0], hs[0][1], hs[0][2],
                hs[1][0], hs[1][1], hs[1][2],
                Wq3[0], Wq3[1], Wq3[2], bq, Q2);
            attn2r<<<RTOT, 256, 0, stream>>>(Q2, ctx, vvec, out, t - 1);
        }
    }
}

// Round 14
// 9197.359 us; speedup vs baseline: 2.1134x; 1.0512x over previous
//
#include <hip/hip_runtime.h>
#include <hip/hip_bf16.h>
#include <math.h>

#define KW 24
#define BSZn 64
#define PLY 32
#define BROWS 1536            // BSZ*KW rows per task
#define RTOT 4608             // 3*BROWS

typedef __attribute__((ext_vector_type(8))) short short8v;  // 8 bf16 (4 VGPRs)
typedef __attribute__((ext_vector_type(4))) float f32x4;

__device__ __forceinline__ float sigmoidf_(float x) { return 1.0f / (1.0f + expf(-x)); }

// async global->LDS, 16B/lane; LDS dest = wave-uniform base + lane*16 (HW scatter)
__device__ __forceinline__ void gload16(const void* g, void* l)
{
    __builtin_amdgcn_global_load_lds(
        (__attribute__((address_space(1))) void*)g,
        (__attribute__((address_space(3))) void*)l, 16, 0, 0);
}

// exact 3-way bf16 split: v = s0 + s1 + s2 + O(2^-26 v)
__device__ __forceinline__ void split3(float v, ushort* a, ushort* b, ushort* c)
{
    __hip_bfloat16 h1 = __float2bfloat16(v);  float f1 = __bfloat162float(h1);
    float r1 = v - f1;
    __hip_bfloat16 h2 = __float2bfloat16(r1); float f2 = __bfloat162float(h2);
    float r2 = r1 - f2;
    __hip_bfloat16 h3 = __float2bfloat16(r2);
    *a = *(ushort*)&h1; *b = *(ushort*)&h2; *c = *(ushort*)&h3;
}

// ---- weights prep (R9-proven, verbatim) ----
__global__ void prep_split(const float* __restrict__ W_ih, const float* __restrict__ W_hh,
                           const float* __restrict__ Wq,
                           const float* __restrict__ b_ih, const float* __restrict__ b_hh,
                           ushort* __restrict__ Wg0, ushort* __restrict__ Wg1, ushort* __restrict__ Wg2,
                           ushort* __restrict__ Wq0, ushort* __restrict__ Wq1, ushort* __restrict__ Wq2,
                           float* __restrict__ biasG)
{
    int n = blockIdx.x, tid = threadIdx.x;     // 0..2559
    if (n < 2048) {
        int ublk = n >> 6, gate = (n >> 4) & 3, ui = n & 15;
        int src = gate * 512 + ublk * 16 + ui;
        for (int k = tid; k < 1024; k += 256) {
            float v = (k < 512) ? W_ih[(size_t)src * 512 + k]
                                : W_hh[(size_t)src * 512 + (k - 512)];
            ushort s0, s1, s2; split3(v, &s0, &s1, &s2);
            Wg0[(size_t)n * 1024 + k] = s0;
            Wg1[(size_t)n * 1024 + k] = s1;
            Wg2[(size_t)n * 1024 + k] = s2;
        }
        if (tid == 0) biasG[src] = b_ih[src] + b_hh[src];
    } else {
        int n2 = n - 2048;
        for (int k = tid; k < 512; k += 256) {
            ushort s0, s1, s2; split3(Wq[(size_t)n2 * 512 + k], &s0, &s1, &s2);
            Wq0[(size_t)n2 * 512 + k] = s0;
            Wq1[(size_t)n2 * 512 + k] = s1;
            Wq2[(size_t)n2 * 512 + k] = s2;
        }
    }
}

// ---- init (R9-proven, verbatim) ----
__global__ void initsplit(const float* __restrict__ home, const float* __restrict__ vis,
                          const float* __restrict__ team, const float* __restrict__ init_embed,
                          float* __restrict__ cst,
                          ushort* __restrict__ h0_, ushort* __restrict__ h1_, ushort* __restrict__ h2_,
                          ushort* __restrict__ x0_, ushort* __restrict__ x1_, ushort* __restrict__ x2_)
{
    int row = blockIdx.x, tid = threadIdx.x;
    int tau = row / BROWS, r = row % BROWS;
    const float* enc = (tau == 0) ? home : (tau == 1) ? vis : team;
    const float* base = enc + ((size_t)((r % KW) * BSZn + r / KW) * PLY) * 512;
    for (int e = tid; e < 512; e += 256) {
        float s = 0.0f;
        for (int p = 0; p < PLY; ++p) s += base[(size_t)p * 512 + e];
        size_t o = (size_t)row * 512 + e;
        cst[o] = s;
        ushort a, b, c;
        split3(s, &a, &b, &c);
        h0_[o] = a; h1_[o] = b; h2_[o] = c;
        split3(init_embed[e], &a, &b, &c);
        x0_[o] = a; x1_[o] = b; x2_[o] = c;
    }
}

// ---- gather x_{t+1} and split (R9-proven, verbatim) ----
__global__ void xprep(const float* __restrict__ home, const float* __restrict__ vis,
                      const float* __restrict__ team,
                      const int* __restrict__ hidx, const int* __restrict__ vidx,
                      const int* __restrict__ tidx,
                      ushort* __restrict__ x0_, ushort* __restrict__ x1_, ushort* __restrict__ x2_,
                      int t)
{
    int row = blockIdx.x, tid = threadIdx.x;
    int tau = row / BROWS, r = row % BROWS;
    const float* enc = (tau == 0) ? home : (tau == 1) ? vis : team;
    const int* idx = (tau == 0) ? hidx : (tau == 1) ? vidx : tidx;
    int j = idx[r * PLY + t];
    const float* src = enc + ((size_t)((r % KW) * BSZn + r / KW) * PLY + j) * 512;
    for (int e = tid; e < 512; e += 256) {
        size_t o = (size_t)row * 512 + e;
        ushort a, b, c; split3(src[e], &a, &b, &c);
        x0_[o] = a; x1_[o] = b; x2_[o] = c;
    }
}

// ---- gates MFMA v14: R13 A-plane grouping + global_load_lds staging ----
// LDS regions (8 KB each): A | B0 | B1 | B2. Region layout: row*64B (32 bf16/kb),
// written by HW scatter lane*16: lane l of wave w, issue j -> row w*32+j*16+(l>>2),
// col16 = l&3 (matches frag-read addressing, identical to R13).
__global__ __launch_bounds__(256) void gates_mfma(
    const ushort* __restrict__ x0_, const ushort* __restrict__ x1_, const ushort* __restrict__ x2_,
    const ushort* __restrict__ hi0, const ushort* __restrict__ hi1, const ushort* __restrict__ hi2,
    const ushort* __restrict__ Wg0, const ushort* __restrict__ Wg1, const ushort* __restrict__ Wg2,
    const float* __restrict__ biasG, float* __restrict__ cst,
    ushort* __restrict__ ho0, ushort* __restrict__ ho1, ushort* __restrict__ ho2)
{
    __shared__ char Lds[32768];               // A | B0 | B1 | B2
    int tid = threadIdx.x;
    int bm = blockIdx.x, bn = blockIdx.y;
    int w = tid >> 6, lane = tid & 63;
    int wr = w >> 1, wc = w & 1;
    int r0 = bm * 128;
    int nbase = bn * 128;
    int l4 = lane >> 2, lc = lane & 3;        // loader row-sub / col16

    const ushort* Ax[3] = {x0_, x1_, x2_};
    const ushort* Ah[3] = {hi0, hi1, hi2};
    const ushort* Bg[3] = {Wg0, Wg1, Wg2};

    f32x4 acc[4][4];
    #pragma unroll
    for (int i = 0; i < 4; ++i)
        #pragma unroll
        for (int j = 0; j < 4; ++j) acc[i][j] = (f32x4){0.f, 0.f, 0.f, 0.f};

    char* ldsW = Lds + w * 2048;              // wave-uniform region base (A region)

    for (int kb = 0; kb < 32; ++kb) {
        int kloc = (kb & 15) * 32;
        bool usex = (kb < 16);
        __syncthreads();                      // prev kb's region reads done
        {
            const ushort* Ap = (usex ? Ax[0] : Ah[0]);
            gload16(Ap + (size_t)(r0 + w * 32 + l4) * 512 + kloc + lc * 8,      ldsW);
            gload16(Ap + (size_t)(r0 + w * 32 + 16 + l4) * 512 + kloc + lc * 8, ldsW + 1024);
            #pragma unroll
            for (int p = 0; p < 3; ++p) {
                gload16(Bg[p] + (size_t)(nbase + w * 32 + l4) * 1024 + kb * 32 + lc * 8,
                        ldsW + (1 + p) * 8192);
                gload16(Bg[p] + (size_t)(nbase + w * 32 + 16 + l4) * 1024 + kb * 32 + lc * 8,
                        ldsW + (1 + p) * 8192 + 1024);
            }
        }
        __syncthreads();                      // vmcnt(0) drained by compiler

        #pragma unroll
        for (int a = 0; a < 3; ++a) {
            if (a > 0) {
                const ushort* Ap = (usex ? Ax[a] : Ah[a]);
                __syncthreads();              // prev A-plane frag reads done
                gload16(Ap + (size_t)(r0 + w * 32 + l4) * 512 + kloc + lc * 8,      ldsW);
                gload16(Ap + (size_t)(r0 + w * 32 + 16 + l4) * 512 + kloc + lc * 8, ldsW + 1024);
                __syncthreads();
            }
            short8v af[4];
            #pragma unroll
            for (int fm = 0; fm < 4; ++fm)
                af[fm] = *(const short8v*)(Lds + (wr * 64 + fm * 16 + (lane & 15)) * 64 + (lane >> 4) * 16);
            #pragma unroll
            for (int b = 2; b >= 0; --b) {    // smallest products first within group
                if (a + b > 2) continue;
                const char* LdsB = Lds + 8192 + b * 8192;
                short8v bf[4];
                #pragma unroll
                for (int fn = 0; fn < 4; ++fn)
                    bf[fn] = *(const short8v*)(LdsB + (wc * 64 + fn * 16 + (lane & 15)) * 64 + (lane >> 4) * 16);
                #pragma unroll
                for (int fm = 0; fm < 4; ++fm)
                    #pragma unroll
                    for (int fn = 0; fn < 4; ++fn)
                        acc[fm][fn] = __builtin_amdgcn_mfma_f32_16x16x32_bf16(
                            af[fm], bf[fn], acc[fm][fn], 0, 0, 0);
            }
        }
    }

    // LSTM epilogue (R9-proven): frag fn == gate; unit u fixed per lane.
    int u = (bn * 2 + wc) * 16 + (lane & 15);
    float bI = biasG[u], bF = biasG[512 + u], bG = biasG[1024 + u], bO = biasG[1536 + u];
    #pragma unroll
    for (int fm = 0; fm < 4; ++fm) {
        #pragma unroll
        for (int reg = 0; reg < 4; ++reg) {
            int row = r0 + wr * 64 + fm * 16 + (lane >> 4) * 4 + reg;
            float gi = acc[fm][0][reg] + bI;
            float gf = acc[fm][1][reg] + bF;
            float gg = acc[fm][2][reg] + bG;
            float go = acc[fm][3][reg] + bO;
            size_t ci = (size_t)row * 512 + u;
            float c = cst[ci];
            c = sigmoidf_(gf) * c + sigmoidf_(gi) * tanhf(gg);
            float h = sigmoidf_(go) * tanhf(c);
            cst[ci] = c;
            ushort s0, s1, s2; split3(h, &s0, &s1, &s2);
            ho0[ci] = s0; ho1[ci] = s1; ho2[ci] = s2;
        }
    }
}

// ---- q2 MFMA v14: grouped passes + global_load_lds (same pattern as gates) ----
// slot 0: q_{t-1} from hA; slot 1: q_t from hB. K=512 (16 kb).
__global__ __launch_bounds__(256) void q2_mfma(
    const ushort* __restrict__ hA0, const ushort* __restrict__ hA1, const ushort* __restrict__ hA2,
    const ushort* __restrict__ hB0, const ushort* __restrict__ hB1, const ushort* __restrict__ hB2,
    const ushort* __restrict__ Wq0, const ushort* __restrict__ Wq1, const ushort* __restrict__ Wq2,
    const float* __restrict__ bq, float* __restrict__ Q2)
{
    __shared__ char Lds[32768];               // A | B0 | B1 | B2
    int tid = threadIdx.x;
    int bm = blockIdx.x, bn = blockIdx.y, slot = blockIdx.z;
    int w = tid >> 6, lane = tid & 63;
    int wr = w >> 1, wc = w & 1;
    int r0 = bm * 128;
    int nbase = bn * 128;
    int l4 = lane >> 2, lc = lane & 3;

    const ushort* Ah[3];
    if (slot == 0) { Ah[0] = hA0; Ah[1] = hA1; Ah[2] = hA2; }
    else           { Ah[0] = hB0; Ah[1] = hB1; Ah[2] = hB2; }
    float* Qout = Q2 + (size_t)slot * RTOT * 512;
    const ushort* Bg[3] = {Wq0, Wq1, Wq2};

    f32x4 acc[4][4];
    #pragma unroll
    for (int i = 0; i < 4; ++i)
        #pragma unroll
        for (int j = 0; j < 4; ++j) acc[i][j] = (f32x4){0.f, 0.f, 0.f, 0.f};

    char* ldsW = Lds + w * 2048;

    for (int kb = 0; kb < 16; ++kb) {
        int kloc = kb * 32;
        __syncthreads();
        {
            gload16(Ah[0] + (size_t)(r0 + w * 32 + l4) * 512 + kloc + lc * 8,      ldsW);
            gload16(Ah[0] + (size_t)(r0 + w * 32 + 16 + l4) * 512 + kloc + lc * 8, ldsW + 1024);
            #pragma unroll
            for (int p = 0; p < 3; ++p) {
                gload16(Bg[p] + (size_t)(nbase + w * 32 + l4) * 512 + kloc + lc * 8,
                        ldsW + (1 + p) * 8192);
                gload16(Bg[p] + (size_t)(nbase + w * 32 + 16 + l4) * 512 + kloc + lc * 8,
                        ldsW + (1 + p) * 8192 + 1024);
            }
        }
        __syncthreads();

        #pragma unroll
        for (int a = 0; a < 3; ++a) {
            if (a > 0) {
                __syncthreads();
                gload16(Ah[a] + (size_t)(r0 + w * 32 + l4) * 512 + kloc + lc * 8,      ldsW);
                gload16(Ah[a] + (size_t)(r0 + w * 32 + 16 + l4) * 512 + kloc + lc * 8, ldsW + 1024);
                __syncthreads();
            }
            short8v af[4];
            #pragma unroll
            for (int fm = 0; fm < 4; ++fm)
                af[fm] = *(const short8v*)(Lds + (wr * 64 + fm * 16 + (lane & 15)) * 64 + (lane >> 4) * 16);
            #pragma unroll
            for (int b = 2; b >= 0; --b) {
                if (a + b > 2) continue;
                const char* LdsB = Lds + 8192 + b * 8192;
                short8v bf[4];
                #pragma unroll
                for (int fn = 0; fn < 4; ++fn)
                    bf[fn] = *(const short8v*)(LdsB + (wc * 64 + fn * 16 + (lane & 15)) * 64 + (lane >> 4) * 16);
                #pragma unroll
                for (int fm = 0; fm < 4; ++fm)
                    #pragma unroll
                    for (int fn = 0; fn < 4; ++fn)
                        acc[fm][fn] = __builtin_amdgcn_mfma_f32_16x16x32_bf16(
                            af[fm], bf[fn], acc[fm][fn], 0, 0, 0);
            }
        }
    }

    #pragma unroll
    for (int fn = 0; fn < 4; ++fn) {
        int col = nbase + wc * 64 + fn * 16 + (lane & 15);
        float bqv = bq[col];
        #pragma unroll
        for (int fm = 0; fm < 4; ++fm)
            #pragma unroll
            for (int reg = 0; reg < 4; ++reg) {
                int row = r0 + wr * 64 + fm * 16 + (lane >> 4) * 4 + reg;
                Qout[(size_t)row * 512 + col] = acc[fm][fn][reg] + bqv;
            }
    }
}

// ---- ctx = enc @ Wc^T, f32 (R1-proven kernel, verbatim) ----
#define BM 128
#define BN 128
#define BKK 16
__global__ __launch_bounds__(256) void gemm_ctx(
    const float* __restrict__ A0, const float* __restrict__ A1, const float* __restrict__ A2,
    const float* __restrict__ B, float* __restrict__ C)
{
    __shared__ float As[BKK][BM + 4];
    __shared__ float Bs[BKK][BN + 4];
    int bm = blockIdx.x, bn = blockIdx.y;
    int tid = threadIdx.x;
    int tm = tid >> 4, tn = tid & 15;
    int lrow = tid >> 2, lc4 = tid & 3;

    int R0 = bm * BM;
    int tau = R0 / (BROWS * PLY);
    const float* enc = (tau == 0) ? A0 : (tau == 1) ? A1 : A2;
    int R = R0 + lrow;
    int rr = R % (BROWS * PLY); int r = rr >> 5; int p = rr & 31;
    const float* a_src0 = enc + (((size_t)((r % KW) * BSZn + r / KW)) * PLY + p) * 512;
    R = R0 + lrow + 64;
    rr = R % (BROWS * PLY); r = rr >> 5; p = rr & 31;
    const float* a_src1 = enc + (((size_t)((r % KW) * BSZn + r / KW)) * PLY + p) * 512;
    const float* b_src0 = B + (size_t)(bn * BN + lrow) * 512;
    const float* b_src1 = b_src0 + (size_t)64 * 512;

    float acc[8][8];
    #pragma unroll
    for (int i = 0; i < 8; ++i)
        #pragma unroll
        for (int j = 0; j < 8; ++j) acc[i][j] = 0.0f;

    float4 a0 = *(const float4*)(a_src0 + lc4 * 4);
    float4 a1 = *(const float4*)(a_src1 + lc4 * 4);
    float4 b0 = *(const float4*)(b_src0 + lc4 * 4);
    float4 b1 = *(const float4*)(b_src1 + lc4 * 4);

    for (int t = 0; t < 512 / BKK; ++t) {
        __syncthreads();
        As[lc4 * 4 + 0][lrow] = a0.x; As[lc4 * 4 + 1][lrow] = a0.y;
        As[lc4 * 4 + 2][lrow] = a0.z; As[lc4 * 4 + 3][lrow] = a0.w;
        As[lc4 * 4 + 0][lrow + 64] = a1.x; As[lc4 * 4 + 1][lrow + 64] = a1.y;
        As[lc4 * 4 + 2][lrow + 64] = a1.z; As[lc4 * 4 + 3][lrow + 64] = a1.w;
        Bs[lc4 * 4 + 0][lrow] = b0.x; Bs[lc4 * 4 + 1][lrow] = b0.y;
        Bs[lc4 * 4 + 2][lrow] = b0.z; Bs[lc4 * 4 + 3][lrow] = b0.w;
        Bs[lc4 * 4 + 0][lrow + 64] = b1.x; Bs[lc4 * 4 + 1][lrow + 64] = b1.y;
        Bs[lc4 * 4 + 2][lrow + 64] = b1.z; Bs[lc4 * 4 + 3][lrow + 64] = b1.w;
        __syncthreads();
        if (t + 1 < 512 / BKK) {
            int k0 = (t + 1) * BKK + lc4 * 4;
            a0 = *(const float4*)(a_src0 + k0);
            a1 = *(const float4*)(a_src1 + k0);
            b0 = *(const float4*)(b_src0 + k0);
            b1 = *(const float4*)(b_src1 + k0);
        }
        #pragma unroll
        for (int k = 0; k < BKK; ++k) {
            float af[8], bf[8];
            *(float4*)&af[0] = *(const float4*)&As[k][tm * 8];
            *(float4*)&af[4] = *(const float4*)&As[k][tm * 8 + 4];
            *(float4*)&bf[0] = *(const float4*)&Bs[k][tn * 8];
            *(float4*)&bf[4] = *(const float4*)&Bs[k][tn * 8 + 4];
            #pragma unroll
            for (int i = 0; i < 8; ++i)
                #pragma unroll
                for (int j = 0; j < 8; ++j)
                    acc[i][j] = fmaf(af[i], bf[j], acc[i][j]);
        }
    }
    int row0 = bm * BM + tm * 8;
    int col0 = bn * BN + tn * 8;
    #pragma unroll
    for (int i = 0; i < 8; ++i) {
        float* cr = C + (size_t)(row0 + i) * 512 + col0;
        float4 o0, o1;
        o0.x = acc[i][0]; o0.y = acc[i][1]; o0.z = acc[i][2]; o0.w = acc[i][3];
        o1.x = acc[i][4]; o1.y = acc[i][5]; o1.z = acc[i][6]; o1.w = acc[i][7];
        *(float4*)cr = o0;
        *(float4*)(cr + 4) = o1;
    }
}

// ---- attention, 2 steps per ctx load (R10/R12-proven, verbatim) ----
__global__ __launch_bounds__(256) void attn2r(
    const float* __restrict__ Q2, const float* __restrict__ ctx,
    const float* __restrict__ vvec, float* __restrict__ out, int tbase)
{
    int row = blockIdx.x, tid = threadIdx.x;
    int w = tid >> 6, lane = tid & 63;
    __shared__ float scs[2][PLY];

    const float* q0 = Q2 + (size_t)row * 512 + lane * 8;                 // slot 0 (even step)
    const float* q1 = Q2 + ((size_t)RTOT + row) * 512 + lane * 8;        // slot 1
    const float* ctxr = ctx + (size_t)row * PLY * 512 + lane * 8;
    float qa[8], qb[8], vv[8];
    *(float4*)&qa[0] = *(const float4*)(q0);
    *(float4*)&qa[4] = *(const float4*)(q0 + 4);
    *(float4*)&qb[0] = *(const float4*)(q1);
    *(float4*)&qb[4] = *(const float4*)(q1 + 4);
    *(float4*)&vv[0] = *(const float4*)(vvec + lane * 8);
    *(float4*)&vv[4] = *(const float4*)(vvec + lane * 8 + 4);

    for (int pp = 0; pp < 8; ++pp) {
        int p = w * 8 + pp;
        const float* cp = ctxr + (size_t)p * 512;
        float cv[8];
        *(float4*)&cv[0] = *(const float4*)(cp);
        *(float4*)&cv[4] = *(const float4*)(cp + 4);
        float a0 = 0.0f, a1 = 0.0f;
        #pragma unroll
        for (int j = 0; j < 8; ++j) {
            a0 += tanhf(qa[j] + cv[j]) * vv[j];
            a1 += tanhf(qb[j] + cv[j]) * vv[j];
        }
        #pragma unroll
        for (int off = 1; off < 64; off <<= 1) {
            a0 += __shfl_xor(a0, off);
            a1 += __shfl_xor(a1, off);
        }
        if (lane == 0) { scs[0][p] = a0; scs[1][p] = a1; }
    }
    __syncthreads();

    if (tid < 64) {
        int w2 = tid >> 5, l = tid & 31;
        float x = scs[w2][l];
        float bvv = x; int bi = l;
        #pragma unroll
        for (int off = 1; off < 32; off <<= 1) {
            float ov = __shfl_xor(bvv, off, 32);
            int oi = __shfl_xor(bi, off, 32);
            if (ov > bvv || (ov == bvv && oi < bi)) { bvv = ov; bi = oi; }
        }
        float s = expf(x - bvv);
        #pragma unroll
        for (int off = 1; off < 32; off <<= 1) s += __shfl_xor(s, off, 32);
        float lse = logf(s);
        int t = tbase + w2;
        int tau = row / BROWS, r = row % BROWS;
        out[(size_t)tau * (BROWS * 1024) + (size_t)r * 1024 + t * 32 + l] = x - bvv - lse;
        if (l == 0)
            out[(size_t)3 * (BROWS * 1024) + (size_t)tau * (BROWS * 32) + r * 32 + t] = (float)bi;
    }
}

extern "C" void kernel_launch(void* const* d_in, const int* in_sizes, int n_in,
                              void* d_out, int out_size, void* d_ws, size_t ws_size,
                              hipStream_t stream)
{
    const float* home = (const float*)d_in[0];
    const int*   hidx = (const int*)d_in[1];
    const float* vis  = (const float*)d_in[2];
    const int*   vidx = (const int*)d_in[3];
    const float* team = (const float*)d_in[4];
    const int*   tidx = (const int*)d_in[5];
    const float* init_embed = (const float*)d_in[6];
    const float* W_ih = (const float*)d_in[7];
    const float* W_hh = (const float*)d_in[8];
    const float* b_ih = (const float*)d_in[9];
    const float* b_hh = (const float*)d_in[10];
    const float* Wq   = (const float*)d_in[11];
    const float* bq   = (const float*)d_in[12];
    const float* Wc   = (const float*)d_in[13];
    const float* vvec = (const float*)d_in[14];
    float* out = (float*)d_out;
    (void)in_sizes; (void)n_in; (void)out_size; (void)ws_size;

    char* wsb = (char*)d_ws;
    float* ctx   = (float*)wsb; wsb += (size_t)RTOT * PLY * 512 * 4;   // 302.0 MB
    float* cst   = (float*)wsb; wsb += (size_t)RTOT * 512 * 4;         // 9.4 MB
    float* Q2    = (float*)wsb; wsb += (size_t)2 * RTOT * 512 * 4;     // 18.9 MB
    float* biasG = (float*)wsb; wsb += 2048 * 4;
    ushort* Wg[3], *Wq3[3], *xs[3], *hs[2][3];
    for (int i = 0; i < 3; ++i) { Wg[i]  = (ushort*)wsb; wsb += (size_t)2048 * 1024 * 2; }
    for (int i = 0; i < 3; ++i) { Wq3[i] = (ushort*)wsb; wsb += (size_t)512 * 512 * 2; }
    for (int i = 0; i < 3; ++i) { xs[i]  = (ushort*)wsb; wsb += (size_t)RTOT * 512 * 2; }
    for (int b = 0; b < 2; ++b)
        for (int i = 0; i < 3; ++i) { hs[b][i] = (ushort*)wsb; wsb += (size_t)RTOT * 512 * 2; }
    // total ~386.9 MB (proven fit in R9)

    prep_split<<<2560, 256, 0, stream>>>(W_ih, W_hh, Wq, b_ih, b_hh,
                                         Wg[0], Wg[1], Wg[2], Wq3[0], Wq3[1], Wq3[2], biasG);
    initsplit<<<RTOT, 256, 0, stream>>>(home, vis, team, init_embed, cst,
                                        hs[1][0], hs[1][1], hs[1][2],
                                        xs[0], xs[1], xs[2]);
    gemm_ctx<<<dim3(RTOT * PLY / BM, 512 / BN), 256, 0, stream>>>(home, vis, team, Wc, ctx);

    for (int t = 0; t < 32; ++t) {
        int hin = (t + 1) & 1, hout = t & 1;
        gates_mfma<<<dim3(36, 16), 256, 0, stream>>>(
            xs[0], xs[1], xs[2],
            hs[hin][0], hs[hin][1], hs[hin][2],
            Wg[0], Wg[1], Wg[2], biasG, cst,
            hs[hout][0], hs[hout][1], hs[hout][2]);
        if (t < 31)
            xprep<<<RTOT, 256, 0, stream>>>(home, vis, team, hidx, vidx, tidx,
                                            xs[0], xs[1], xs[2], t);
        if (t & 1) {
            // h_{t-1} in hs[0], h_t in hs[1]: compute q_{t-1} (slot 0) + q_t (slot 1)
            q2_mfma<<<dim3(36, 4, 2), 256, 0, stream>>>(
                hs[0][0], hs[0][1], hs[0][2],
                hs[1][0], hs[1][1], hs[1][2],
                Wq3[0], Wq3[1], Wq3[2], bq, Q2);
            attn2r<<<RTOT, 256, 0, stream>>>(Q2, ctx, vvec, out, t - 1);
        }
    }
}

// Round 15
// 8598.967 us; speedup vs baseline: 2.2605x; 1.0696x over previous
//
#include <hip/hip_runtime.h>
#include <hip/hip_bf16.h>
#include <math.h>

#define KW 24
#define BSZn 64
#define PLY 32
#define BROWS 1536            // BSZ*KW rows per task
#define RTOT 4608             // 3*BROWS

typedef __attribute__((ext_vector_type(8))) short short8v;  // 8 bf16 (4 VGPRs)
typedef __attribute__((ext_vector_type(4))) float f32x4;

__device__ __forceinline__ float sigmoidf_(float x) { return 1.0f / (1.0f + expf(-x)); }

// async global->LDS, 16B/lane; LDS dest = wave-uniform base + lane*16 (HW scatter)
__device__ __forceinline__ void gload16(const void* g, void* l)
{
    __builtin_amdgcn_global_load_lds(
        (__attribute__((address_space(1))) void*)g,
        (__attribute__((address_space(3))) void*)l, 16, 0, 0);
}

// exact 3-way bf16 split: v = s0 + s1 + s2 + O(2^-26 v)
__device__ __forceinline__ void split3(float v, ushort* a, ushort* b, ushort* c)
{
    __hip_bfloat16 h1 = __float2bfloat16(v);  float f1 = __bfloat162float(h1);
    float r1 = v - f1;
    __hip_bfloat16 h2 = __float2bfloat16(r1); float f2 = __bfloat162float(h2);
    float r2 = r1 - f2;
    __hip_bfloat16 h3 = __float2bfloat16(r2);
    *a = *(ushort*)&h1; *b = *(ushort*)&h2; *c = *(ushort*)&h3;
}

// ---- weights prep (R9-proven, verbatim) ----
__global__ void prep_split(const float* __restrict__ W_ih, const float* __restrict__ W_hh,
                           const float* __restrict__ Wq,
                           const float* __restrict__ b_ih, const float* __restrict__ b_hh,
                           ushort* __restrict__ Wg0, ushort* __restrict__ Wg1, ushort* __restrict__ Wg2,
                           ushort* __restrict__ Wq0, ushort* __restrict__ Wq1, ushort* __restrict__ Wq2,
                           float* __restrict__ biasG)
{
    int n = blockIdx.x, tid = threadIdx.x;     // 0..2559
    if (n < 2048) {
        int ublk = n >> 6, gate = (n >> 4) & 3, ui = n & 15;
        int src = gate * 512 + ublk * 16 + ui;
        for (int k = tid; k < 1024; k += 256) {
            float v = (k < 512) ? W_ih[(size_t)src * 512 + k]
                                : W_hh[(size_t)src * 512 + (k - 512)];
            ushort s0, s1, s2; split3(v, &s0, &s1, &s2);
            Wg0[(size_t)n * 1024 + k] = s0;
            Wg1[(size_t)n * 1024 + k] = s1;
            Wg2[(size_t)n * 1024 + k] = s2;
        }
        if (tid == 0) biasG[src] = b_ih[src] + b_hh[src];
    } else {
        int n2 = n - 2048;
        for (int k = tid; k < 512; k += 256) {
            ushort s0, s1, s2; split3(Wq[(size_t)n2 * 512 + k], &s0, &s1, &s2);
            Wq0[(size_t)n2 * 512 + k] = s0;
            Wq1[(size_t)n2 * 512 + k] = s1;
            Wq2[(size_t)n2 * 512 + k] = s2;
        }
    }
}

// ---- init (R9-proven, verbatim) ----
__global__ void initsplit(const float* __restrict__ home, const float* __restrict__ vis,
                          const float* __restrict__ team, const float* __restrict__ init_embed,
                          float* __restrict__ cst,
                          ushort* __restrict__ h0_, ushort* __restrict__ h1_, ushort* __restrict__ h2_,
                          ushort* __restrict__ x0_, ushort* __restrict__ x1_, ushort* __restrict__ x2_)
{
    int row = blockIdx.x, tid = threadIdx.x;
    int tau = row / BROWS, r = row % BROWS;
    const float* enc = (tau == 0) ? home : (tau == 1) ? vis : team;
    const float* base = enc + ((size_t)((r % KW) * BSZn + r / KW) * PLY) * 512;
    for (int e = tid; e < 512; e += 256) {
        float s = 0.0f;
        for (int p = 0; p < PLY; ++p) s += base[(size_t)p * 512 + e];
        size_t o = (size_t)row * 512 + e;
        cst[o] = s;
        ushort a, b, c;
        split3(s, &a, &b, &c);
        h0_[o] = a; h1_[o] = b; h2_[o] = c;
        split3(init_embed[e], &a, &b, &c);
        x0_[o] = a; x1_[o] = b; x2_[o] = c;
    }
}

// ---- gather x_{t+1} and split (R9-proven, verbatim) ----
__global__ void xprep(const float* __restrict__ home, const float* __restrict__ vis,
                      const float* __restrict__ team,
                      const int* __restrict__ hidx, const int* __restrict__ vidx,
                      const int* __restrict__ tidx,
                      ushort* __restrict__ x0_, ushort* __restrict__ x1_, ushort* __restrict__ x2_,
                      int t)
{
    int row = blockIdx.x, tid = threadIdx.x;
    int tau = row / BROWS, r = row % BROWS;
    const float* enc = (tau == 0) ? home : (tau == 1) ? vis : team;
    const int* idx = (tau == 0) ? hidx : (tau == 1) ? vidx : tidx;
    int j = idx[r * PLY + t];
    const float* src = enc + ((size_t)((r % KW) * BSZn + r / KW) * PLY + j) * 512;
    for (int e = tid; e < 512; e += 256) {
        size_t o = (size_t)row * 512 + e;
        ushort a, b, c; split3(src[e], &a, &b, &c);
        x0_[o] = a; x1_[o] = b; x2_[o] = c;
    }
}

// ---- gates+q MFMA v15: R14 kernel + fused q blocks ----
// bn (= blockIdx.y + bn_off) < 16: gates (K=1024, x|h, LSTM epilogue).
// bn in 16..19: q_{t-1} = hin @ Wq^T + bq -> Q2[qslot] (K=512 = h half; kb 16..31).
// q's A data == gates' hin (h_{t-1}) -> shares the launch. Inner loop identical to R14.
__global__ __launch_bounds__(256) void gates_mfma(
    const ushort* __restrict__ x0_, const ushort* __restrict__ x1_, const ushort* __restrict__ x2_,
    const ushort* __restrict__ hi0, const ushort* __restrict__ hi1, const ushort* __restrict__ hi2,
    const ushort* __restrict__ Wg0, const ushort* __restrict__ Wg1, const ushort* __restrict__ Wg2,
    const ushort* __restrict__ Wq0, const ushort* __restrict__ Wq1, const ushort* __restrict__ Wq2,
    const float* __restrict__ biasG, const float* __restrict__ bq,
    float* __restrict__ cst,
    ushort* __restrict__ ho0, ushort* __restrict__ ho1, ushort* __restrict__ ho2,
    float* __restrict__ Q2, int bn_off, int qslot)
{
    __shared__ char Lds[32768];               // A | B0 | B1 | B2
    int tid = threadIdx.x;
    int bm = blockIdx.x, bn = blockIdx.y + bn_off;
    bool isq = bn >= 16;
    int w = tid >> 6, lane = tid & 63;
    int wr = w >> 1, wc = w & 1;
    int r0 = bm * 128;
    int nbase = isq ? (bn - 16) * 128 : bn * 128;
    int ldb = isq ? 512 : 1024;
    int kb0 = isq ? 16 : 0;
    int l4 = lane >> 2, lc = lane & 3;        // loader row-sub / col16

    const ushort* Ax[3] = {x0_, x1_, x2_};
    const ushort* Ah[3] = {hi0, hi1, hi2};
    const ushort* Bp[3];
    if (isq) { Bp[0] = Wq0; Bp[1] = Wq1; Bp[2] = Wq2; }
    else     { Bp[0] = Wg0; Bp[1] = Wg1; Bp[2] = Wg2; }

    f32x4 acc[4][4];
    #pragma unroll
    for (int i = 0; i < 4; ++i)
        #pragma unroll
        for (int j = 0; j < 4; ++j) acc[i][j] = (f32x4){0.f, 0.f, 0.f, 0.f};

    char* ldsW = Lds + w * 2048;              // wave-uniform region base (A region)

    for (int kb = kb0; kb < 32; ++kb) {
        int kloc = (kb & 15) * 32;            // element offset within x- or h-row
        bool usex = (!isq) && (kb < 16);
        int bofe = isq ? kloc : kb * 32;      // element offset within B row
        __syncthreads();                      // prev kb's region reads done
        {
            const ushort* Ap = (usex ? Ax[0] : Ah[0]);
            gload16(Ap + (size_t)(r0 + w * 32 + l4) * 512 + kloc + lc * 8,      ldsW);
            gload16(Ap + (size_t)(r0 + w * 32 + 16 + l4) * 512 + kloc + lc * 8, ldsW + 1024);
            #pragma unroll
            for (int p = 0; p < 3; ++p) {
                gload16(Bp[p] + (size_t)(nbase + w * 32 + l4) * ldb + bofe + lc * 8,
                        ldsW + (1 + p) * 8192);
                gload16(Bp[p] + (size_t)(nbase + w * 32 + 16 + l4) * ldb + bofe + lc * 8,
                        ldsW + (1 + p) * 8192 + 1024);
            }
        }
        __syncthreads();                      // vmcnt(0) drained by compiler

        #pragma unroll
        for (int a = 0; a < 3; ++a) {
            if (a > 0) {
                const ushort* Ap = (usex ? Ax[a] : Ah[a]);
                __syncthreads();              // prev A-plane frag reads done
                gload16(Ap + (size_t)(r0 + w * 32 + l4) * 512 + kloc + lc * 8,      ldsW);
                gload16(Ap + (size_t)(r0 + w * 32 + 16 + l4) * 512 + kloc + lc * 8, ldsW + 1024);
                __syncthreads();
            }
            short8v af[4];
            #pragma unroll
            for (int fm = 0; fm < 4; ++fm)
                af[fm] = *(const short8v*)(Lds + (wr * 64 + fm * 16 + (lane & 15)) * 64 + (lane >> 4) * 16);
            #pragma unroll
            for (int b = 2; b >= 0; --b) {    // smallest products first within group
                if (a + b > 2) continue;
                const char* LdsB = Lds + 8192 + b * 8192;
                short8v bf[4];
                #pragma unroll
                for (int fn = 0; fn < 4; ++fn)
                    bf[fn] = *(const short8v*)(LdsB + (wc * 64 + fn * 16 + (lane & 15)) * 64 + (lane >> 4) * 16);
                #pragma unroll
                for (int fm = 0; fm < 4; ++fm)
                    #pragma unroll
                    for (int fn = 0; fn < 4; ++fn)
                        acc[fm][fn] = __builtin_amdgcn_mfma_f32_16x16x32_bf16(
                            af[fm], bf[fn], acc[fm][fn], 0, 0, 0);
            }
        }
    }

    if (!isq) {
        // LSTM epilogue (R9-proven): frag fn == gate; unit u fixed per lane.
        int u = (bn * 2 + wc) * 16 + (lane & 15);
        float bI = biasG[u], bF = biasG[512 + u], bG = biasG[1024 + u], bO = biasG[1536 + u];
        #pragma unroll
        for (int fm = 0; fm < 4; ++fm) {
            #pragma unroll
            for (int reg = 0; reg < 4; ++reg) {
                int row = r0 + wr * 64 + fm * 16 + (lane >> 4) * 4 + reg;
                float gi = acc[fm][0][reg] + bI;
                float gf = acc[fm][1][reg] + bF;
                float gg = acc[fm][2][reg] + bG;
                float go = acc[fm][3][reg] + bO;
                size_t ci = (size_t)row * 512 + u;
                float c = cst[ci];
                c = sigmoidf_(gf) * c + sigmoidf_(gi) * tanhf(gg);
                float h = sigmoidf_(go) * tanhf(c);
                cst[ci] = c;
                ushort s0, s1, s2; split3(h, &s0, &s1, &s2);
                ho0[ci] = s0; ho1[ci] = s1; ho2[ci] = s2;
            }
        }
    } else {
        float* Qout = Q2 + (size_t)qslot * RTOT * 512;
        #pragma unroll
        for (int fn = 0; fn < 4; ++fn) {
            int col = nbase + wc * 64 + fn * 16 + (lane & 15);
            float bqv = bq[col];
            #pragma unroll
            for (int fm = 0; fm < 4; ++fm)
                #pragma unroll
                for (int reg = 0; reg < 4; ++reg) {
                    int row = r0 + wr * 64 + fm * 16 + (lane >> 4) * 4 + reg;
                    Qout[(size_t)row * 512 + col] = acc[fm][fn][reg] + bqv;
                }
        }
    }
}

// ---- ctx = enc @ Wc^T, f32 (R1-proven kernel, verbatim) ----
#define BM 128
#define BN 128
#define BKK 16
__global__ __launch_bounds__(256) void gemm_ctx(
    const float* __restrict__ A0, const float* __restrict__ A1, const float* __restrict__ A2,
    const float* __restrict__ B, float* __restrict__ C)
{
    __shared__ float As[BKK][BM + 4];
    __shared__ float Bs[BKK][BN + 4];
    int bm = blockIdx.x, bn = blockIdx.y;
    int tid = threadIdx.x;
    int tm = tid >> 4, tn = tid & 15;
    int lrow = tid >> 2, lc4 = tid & 3;

    int R0 = bm * BM;
    int tau = R0 / (BROWS * PLY);
    const float* enc = (tau == 0) ? A0 : (tau == 1) ? A1 : A2;
    int R = R0 + lrow;
    int rr = R % (BROWS * PLY); int r = rr >> 5; int p = rr & 31;
    const float* a_src0 = enc + (((size_t)((r % KW) * BSZn + r / KW)) * PLY + p) * 512;
    R = R0 + lrow + 64;
    rr = R % (BROWS * PLY); r = rr >> 5; p = rr & 31;
    const float* a_src1 = enc + (((size_t)((r % KW) * BSZn + r / KW)) * PLY + p) * 512;
    const float* b_src0 = B + (size_t)(bn * BN + lrow) * 512;
    const float* b_src1 = b_src0 + (size_t)64 * 512;

    float acc[8][8];
    #pragma unroll
    for (int i = 0; i < 8; ++i)
        #pragma unroll
        for (int j = 0; j < 8; ++j) acc[i][j] = 0.0f;

    float4 a0 = *(const float4*)(a_src0 + lc4 * 4);
    float4 a1 = *(const float4*)(a_src1 + lc4 * 4);
    float4 b0 = *(const float4*)(b_src0 + lc4 * 4);
    float4 b1 = *(const float4*)(b_src1 + lc4 * 4);

    for (int t = 0; t < 512 / BKK; ++t) {
        __syncthreads();
        As[lc4 * 4 + 0][lrow] = a0.x; As[lc4 * 4 + 1][lrow] = a0.y;
        As[lc4 * 4 + 2][lrow] = a0.z; As[lc4 * 4 + 3][lrow] = a0.w;
        As[lc4 * 4 + 0][lrow + 64] = a1.x; As[lc4 * 4 + 1][lrow + 64] = a1.y;
        As[lc4 * 4 + 2][lrow + 64] = a1.z; As[lc4 * 4 + 3][lrow + 64] = a1.w;
        Bs[lc4 * 4 + 0][lrow] = b0.x; Bs[lc4 * 4 + 1][lrow] = b0.y;
        Bs[lc4 * 4 + 2][lrow] = b0.z; Bs[lc4 * 4 + 3][lrow] = b0.w;
        Bs[lc4 * 4 + 0][lrow + 64] = b1.x; Bs[lc4 * 4 + 1][lrow + 64] = b1.y;
        Bs[lc4 * 4 + 2][lrow + 64] = b1.z; Bs[lc4 * 4 + 3][lrow + 64] = b1.w;
        __syncthreads();
        if (t + 1 < 512 / BKK) {
            int k0 = (t + 1) * BKK + lc4 * 4;
            a0 = *(const float4*)(a_src0 + k0);
            a1 = *(const float4*)(a_src1 + k0);
            b0 = *(const float4*)(b_src0 + k0);
            b1 = *(const float4*)(b_src1 + k0);
        }
        #pragma unroll
        for (int k = 0; k < BKK; ++k) {
            float af[8], bf[8];
            *(float4*)&af[0] = *(const float4*)&As[k][tm * 8];
            *(float4*)&af[4] = *(const float4*)&As[k][tm * 8 + 4];
            *(float4*)&bf[0] = *(const float4*)&Bs[k][tn * 8];
            *(float4*)&bf[4] = *(const float4*)&Bs[k][tn * 8 + 4];
            #pragma unroll
            for (int i = 0; i < 8; ++i)
                #pragma unroll
                for (int j = 0; j < 8; ++j)
                    acc[i][j] = fmaf(af[i], bf[j], acc[i][j]);
        }
    }
    int row0 = bm * BM + tm * 8;
    int col0 = bn * BN + tn * 8;
    #pragma unroll
    for (int i = 0; i < 8; ++i) {
        float* cr = C + (size_t)(row0 + i) * 512 + col0;
        float4 o0, o1;
        o0.x = acc[i][0]; o0.y = acc[i][1]; o0.z = acc[i][2]; o0.w = acc[i][3];
        o1.x = acc[i][4]; o1.y = acc[i][5]; o1.z = acc[i][6]; o1.w = acc[i][7];
        *(float4*)cr = o0;
        *(float4*)(cr + 4) = o1;
    }
}

// ---- attention, 2 steps per ctx load (R10/R12-proven, verbatim) ----
__global__ __launch_bounds__(256) void attn2r(
    const float* __restrict__ Q2, const float* __restrict__ ctx,
    const float* __restrict__ vvec, float* __restrict__ out, int tbase)
{
    int row = blockIdx.x, tid = threadIdx.x;
    int w = tid >> 6, lane = tid & 63;
    __shared__ float scs[2][PLY];

    const float* q0 = Q2 + (size_t)row * 512 + lane * 8;                 // slot 0 (even step)
    const float* q1 = Q2 + ((size_t)RTOT + row) * 512 + lane * 8;        // slot 1
    const float* ctxr = ctx + (size_t)row * PLY * 512 + lane * 8;
    float qa[8], qb[8], vv[8];
    *(float4*)&qa[0] = *(const float4*)(q0);
    *(float4*)&qa[4] = *(const float4*)(q0 + 4);
    *(float4*)&qb[0] = *(const float4*)(q1);
    *(float4*)&qb[4] = *(const float4*)(q1 + 4);
    *(float4*)&vv[0] = *(const float4*)(vvec + lane * 8);
    *(float4*)&vv[4] = *(const float4*)(vvec + lane * 8 + 4);

    for (int pp = 0; pp < 8; ++pp) {
        int p = w * 8 + pp;
        const float* cp = ctxr + (size_t)p * 512;
        float cv[8];
        *(float4*)&cv[0] = *(const float4*)(cp);
        *(float4*)&cv[4] = *(const float4*)(cp + 4);
        float a0 = 0.0f, a1 = 0.0f;
        #pragma unroll
        for (int j = 0; j < 8; ++j) {
            a0 += tanhf(qa[j] + cv[j]) * vv[j];
            a1 += tanhf(qb[j] + cv[j]) * vv[j];
        }
        #pragma unroll
        for (int off = 1; off < 64; off <<= 1) {
            a0 += __shfl_xor(a0, off);
            a1 += __shfl_xor(a1, off);
        }
        if (lane == 0) { scs[0][p] = a0; scs[1][p] = a1; }
    }
    __syncthreads();

    if (tid < 64) {
        int w2 = tid >> 5, l = tid & 31;
        float x = scs[w2][l];
        float bvv = x; int bi = l;
        #pragma unroll
        for (int off = 1; off < 32; off <<= 1) {
            float ov = __shfl_xor(bvv, off, 32);
            int oi = __shfl_xor(bi, off, 32);
            if (ov > bvv || (ov == bvv && oi < bi)) { bvv = ov; bi = oi; }
        }
        float s = expf(x - bvv);
        #pragma unroll
        for (int off = 1; off < 32; off <<= 1) s += __shfl_xor(s, off, 32);
        float lse = logf(s);
        int t = tbase + w2;
        int tau = row / BROWS, r = row % BROWS;
        out[(size_t)tau * (BROWS * 1024) + (size_t)r * 1024 + t * 32 + l] = x - bvv - lse;
        if (l == 0)
            out[(size_t)3 * (BROWS * 1024) + (size_t)tau * (BROWS * 32) + r * 32 + t] = (float)bi;
    }
}

extern "C" void kernel_launch(void* const* d_in, const int* in_sizes, int n_in,
                              void* d_out, int out_size, void* d_ws, size_t ws_size,
                              hipStream_t stream)
{
    const float* home = (const float*)d_in[0];
    const int*   hidx = (const int*)d_in[1];
    const float* vis  = (const float*)d_in[2];
    const int*   vidx = (const int*)d_in[3];
    const float* team = (const float*)d_in[4];
    const int*   tidx = (const int*)d_in[5];
    const float* init_embed = (const float*)d_in[6];
    const float* W_ih = (const float*)d_in[7];
    const float* W_hh = (const float*)d_in[8];
    const float* b_ih = (const float*)d_in[9];
    const float* b_hh = (const float*)d_in[10];
    const float* Wq   = (const float*)d_in[11];
    const float* bq   = (const float*)d_in[12];
    const float* Wc   = (const float*)d_in[13];
    const float* vvec = (const float*)d_in[14];
    float* out = (float*)d_out;
    (void)in_sizes; (void)n_in; (void)out_size; (void)ws_size;

    char* wsb = (char*)d_ws;
    float* ctx   = (float*)wsb; wsb += (size_t)RTOT * PLY * 512 * 4;   // 302.0 MB
    float* cst   = (float*)wsb; wsb += (size_t)RTOT * 512 * 4;         // 9.4 MB
    float* Q2    = (float*)wsb; wsb += (size_t)2 * RTOT * 512 * 4;     // 18.9 MB
    float* biasG = (float*)wsb; wsb += 2048 * 4;
    ushort* Wg[3], *Wq3[3], *xs[3], *hs[2][3];
    for (int i = 0; i < 3; ++i) { Wg[i]  = (ushort*)wsb; wsb += (size_t)2048 * 1024 * 2; }
    for (int i = 0; i < 3; ++i) { Wq3[i] = (ushort*)wsb; wsb += (size_t)512 * 512 * 2; }
    for (int i = 0; i < 3; ++i) { xs[i]  = (ushort*)wsb; wsb += (size_t)RTOT * 512 * 2; }
    for (int b = 0; b < 2; ++b)
        for (int i = 0; i < 3; ++i) { hs[b][i] = (ushort*)wsb; wsb += (size_t)RTOT * 512 * 2; }
    // total ~386.9 MB (proven fit in R9)

    prep_split<<<2560, 256, 0, stream>>>(W_ih, W_hh, Wq, b_ih, b_hh,
                                         Wg[0], Wg[1], Wg[2], Wq3[0], Wq3[1], Wq3[2], biasG);
    initsplit<<<RTOT, 256, 0, stream>>>(home, vis, team, init_embed, cst,
                                        hs[1][0], hs[1][1], hs[1][2],
                                        xs[0], xs[1], xs[2]);
    gemm_ctx<<<dim3(RTOT * PLY / BM, 512 / BN), 256, 0, stream>>>(home, vis, team, Wc, ctx);

    for (int t = 0; t < 32; ++t) {
        int hin = (t + 1) & 1, hout = t & 1;
        int gy = 16 + ((t >= 1) ? 4 : 0);      // t>=1: fuse q_{t-1} (A == hin)
        gates_mfma<<<dim3(36, gy), 256, 0, stream>>>(
            xs[0], xs[1], xs[2],
            hs[hin][0], hs[hin][1], hs[hin][2],
            Wg[0], Wg[1], Wg[2], Wq3[0], Wq3[1], Wq3[2],
            biasG, bq, cst,
            hs[hout][0], hs[hout][1], hs[hout][2],
            Q2, 0, (t - 1) & 1);
        if (t < 31)
            xprep<<<RTOT, 256, 0, stream>>>(home, vis, team, hidx, vidx, tidx,
                                            xs[0], xs[1], xs[2], t);
        if (t >= 2 && (t & 1) == 0)           // q(t-2),q(t-1) both ready
            attn2r<<<RTOT, 256, 0, stream>>>(Q2, ctx, vvec, out, t - 2);
    }
    // tail: q_31 from h_31 (hs[1]); q-only launch (bn_off=16), slot 1
    gates_mfma<<<dim3(36, 4), 256, 0, stream>>>(
        xs[0], xs[1], xs[2],
        hs[1][0], hs[1][1], hs[1][2],
        Wg[0], Wg[1], Wg[2], Wq3[0], Wq3[1], Wq3[2],
        biasG, bq, cst,
        hs[0][0], hs[0][1], hs[0][2],
        Q2, 16, 1);
    attn2r<<<RTOT, 256, 0, stream>>>(Q2, ctx, vvec, out, 30);
}